// Round 4
// baseline (596.182 us; speedup 1.0000x reference)
//
#include <hip/hip_runtime.h>
#include <hip/hip_bf16.h>

typedef __hip_bfloat16 bf16;

#define N_NODE 20000
#define D      128
#define NEDGE  300000

// ---------------------------------------------------------------- small utils
__global__ void fill_i32(int* __restrict__ p, int v, int n) {
    int i = blockIdx.x * blockDim.x + threadIdx.x;
    int stride = gridDim.x * blockDim.x;
    for (; i < n; i += stride) p[i] = v;
}

__global__ void copy_i32(int* __restrict__ dst, const int* __restrict__ src, int n) {
    int i = blockIdx.x * blockDim.x + threadIdx.x;
    int stride = gridDim.x * blockDim.x;
    for (; i < n; i += stride) dst[i] = src[i];
}

// ---------------------------------------------------------------- GEMM + projections
// One block (128 threads) per node. Thread j computes Wh[n][j] in f32,
// stores bf16 (workspace bandwidth hedge; rounding error ~2^-8 * |Wh| ~ 0.004
// vs threshold 0.031); block then reduces Wh[n]·va -> el[n], Wh[n]·vb -> er[n]
// from the full-f32 accumulators, so the softmax inputs stay full precision.
__global__ __launch_bounds__(128) void gemm_proj(
    const float* __restrict__ feat, const float* __restrict__ W,
    const float* __restrict__ bias, const float* __restrict__ va,
    const float* __restrict__ vb, bf16* __restrict__ Wh,
    float* __restrict__ el, float* __restrict__ er) {
    __shared__ float fs[D];
    __shared__ float red[4];
    const int n = blockIdx.x;
    const int j = threadIdx.x;
    fs[j] = feat[n * D + j];
    __syncthreads();
    float acc = 0.f;
#pragma unroll 8
    for (int k = 0; k < D; ++k) acc = fmaf(fs[k], W[k * D + j], acc);
    acc += bias[j];
    Wh[n * D + j] = __float2bfloat16(acc);
    float ea = acc * va[j];
    float eb = acc * vb[j];
#pragma unroll
    for (int off = 32; off > 0; off >>= 1) {
        ea += __shfl_down(ea, off, 64);
        eb += __shfl_down(eb, off, 64);
    }
    const int wave = j >> 6, lane = j & 63;
    if (lane == 0) { red[wave * 2] = ea; red[wave * 2 + 1] = eb; }
    __syncthreads();
    if (j == 0) el[n] = red[0] + red[2];
    else if (j == 1) er[n] = red[1] + red[3];
}

// ---------------------------------------------------------------- CSR build
__global__ __launch_bounds__(256) void hist_dst(
    const int* __restrict__ dst, int* __restrict__ cnt, int E) {
    int i = blockIdx.x * blockDim.x + threadIdx.x;
    int stride = gridDim.x * blockDim.x;
    for (; i < E; i += stride) atomicAdd(&cnt[dst[i]], 1);
}

// single-block exclusive scan: row_ptr[0]=0, row_ptr[i+1]=sum(cnt[0..i])
__global__ __launch_bounds__(1024) void scan_rowptr(
    const int* __restrict__ cnt, int* __restrict__ row_ptr, int n) {
    __shared__ int buf[1024];
    __shared__ int carry;
    if (threadIdx.x == 0) { carry = 0; row_ptr[0] = 0; }
    __syncthreads();
    for (int base = 0; base < n; base += 1024) {
        int i = base + threadIdx.x;
        buf[threadIdx.x] = (i < n) ? cnt[i] : 0;
        __syncthreads();
        for (int off = 1; off < 1024; off <<= 1) {
            int t = (threadIdx.x >= (unsigned)off) ? buf[threadIdx.x - off] : 0;
            __syncthreads();
            buf[threadIdx.x] += t;
            __syncthreads();
        }
        if (i < n) row_ptr[i + 1] = carry + buf[threadIdx.x];
        __syncthreads();
        if (threadIdx.x == 0) carry += buf[1023];
        __syncthreads();
    }
}

// scatter edges into dst-sorted slots; store src idx and pe = exp(leaky(el+er)).
// No max-subtraction: softmax is shift-invariant and |e| <= ~3 here, so exp is
// safely inside f32 range — mathematically identical to the reference.
__global__ __launch_bounds__(256) void csr_scatter(
    const int* __restrict__ src, const int* __restrict__ dst,
    const float* __restrict__ el, const float* __restrict__ er,
    int* __restrict__ cursor, int* __restrict__ edge_src,
    float* __restrict__ edge_pe, int E) {
    int i = blockIdx.x * blockDim.x + threadIdx.x;
    int stride = gridDim.x * blockDim.x;
    for (; i < E; i += stride) {
        const int d = dst[i];
        float v = el[src[i]] + er[d];
        v = v > 0.f ? v : 0.01f * v;
        const int slot = atomicAdd(&cursor[d], 1);
        edge_src[slot] = src[i];
        edge_pe[slot] = expf(v);
    }
}

// ---------------------------------------------------------------- gather
// One wave per dst node; lane l owns output columns {2l, 2l+1}.
// pass 1: wave-parallel sum of pe over the node's edge list.
// pass 2: acc += (pe/sum) * Wh[src] (bf16 pair per lane), f32x2 store to out.
// accumulate!=0: start from the f32 partial already in out (phase-2 sum).
__global__ __launch_bounds__(256) void csr_gather(
    const int* __restrict__ row_ptr, const int* __restrict__ edge_src,
    const float* __restrict__ edge_pe, const bf16* __restrict__ Wh,
    float* __restrict__ out, int n, int accumulate) {
    const int node = blockIdx.x * (blockDim.x >> 6) + (threadIdx.x >> 6);
    const int lane = threadIdx.x & 63;
    if (node >= n) return;
    const int beg = row_ptr[node];
    const int end = row_ptr[node + 1];

    float sum = 0.f;
    for (int i = beg + lane; i < end; i += 64) sum += edge_pe[i];
#pragma unroll
    for (int off = 32; off > 0; off >>= 1) sum += __shfl_down(sum, off, 64);
    sum = __shfl(sum, 0, 64);
    const float inv = (end > beg) ? 1.0f / sum : 0.f;

    float2* outv = (float2*)(out + (size_t)node * D) + lane;
    float a0 = 0.f, a1 = 0.f;
    if (accumulate) {
        const float2 prev = *outv;
        a0 = prev.x;
        a1 = prev.y;
    }
    for (int i = beg; i < end; ++i) {
        const float coef = edge_pe[i] * inv;
        const unsigned u = ((const unsigned*)(Wh + (size_t)edge_src[i] * D))[lane];
        a0 = fmaf(coef, __uint_as_float(u << 16), a0);          // col 2*lane
        a1 = fmaf(coef, __uint_as_float(u & 0xFFFF0000u), a1);  // col 2*lane+1
    }
    *outv = make_float2(a0, a1);
}

extern "C" void kernel_launch(void* const* d_in, const int* in_sizes, int n_in,
                              void* d_out, int out_size, void* d_ws, size_t ws_size,
                              hipStream_t stream) {
    const float* feat_drug    = (const float*)d_in[0];
    const float* feat_disease = (const float*)d_in[1];
    const float* W_ind = (const float*)d_in[2];
    const float* b_ind = (const float*)d_in[3];
    const float* a_ind = (const float*)d_in[4];
    const float* W_rev = (const float*)d_in[5];
    const float* b_rev = (const float*)d_in[6];
    const float* a_rev = (const float*)d_in[7];
    const float* W_dd  = (const float*)d_in[8];
    const float* b_dd  = (const float*)d_in[9];
    const float* a_dd  = (const float*)d_in[10];
    const int* src_ind = (const int*)d_in[11];
    const int* dst_ind = (const int*)d_in[12];
    const int* src_rev = (const int*)d_in[13];
    const int* dst_rev = (const int*)d_in[14];
    const int* src_dd  = (const int*)d_in[15];
    const int* dst_dd  = (const int*)d_in[16];
    float* out = (float*)d_out;
    (void)in_sizes; (void)n_in; (void)out_size; (void)ws_size;

    // ---- workspace: 8,160,032 bytes total ----
    char* w = (char*)d_ws;
    bf16*  Wh      = (bf16*)w;                    // 5,120,000 B (shared by all etypes)
    float* el_ind  = (float*)(w + 5120000);       // 6 x 80,000 B
    float* er_ind  = (float*)(w + 5200000);
    float* el_rev  = (float*)(w + 5280000);
    float* er_rev  = (float*)(w + 5360000);
    float* el_dd   = (float*)(w + 5440000);
    float* er_dd   = (float*)(w + 5520000);
    int*   row_ptr = (int*)(w + 5600000);         // 80,004 B (padded to 80,032)
    int*   cnt     = (int*)(w + 5680032);         // 80,000 B (also cursor)
    int*   edge_src= (int*)(w + 5760032);         // 1,200,000 B
    float* edge_pe = (float*)(w + 6960032);       // 1,200,000 B -> end 8,160,032

    const int hn = N_NODE * D;
    const int eb = (NEDGE + 255) / 256;
    const int nb = (N_NODE + 255) / 256;
    const int gb = (N_NODE + 3) / 4;  // csr_gather: 4 waves/block, 1 node/wave

#define BUILD_CSR(SRC, DST, EL, ER)                                            \
    fill_i32<<<nb, 256, 0, stream>>>(cnt, 0, N_NODE);                          \
    hist_dst<<<eb, 256, 0, stream>>>(DST, cnt, NEDGE);                         \
    scan_rowptr<<<1, 1024, 0, stream>>>(cnt, row_ptr, N_NODE);                 \
    copy_i32<<<nb, 256, 0, stream>>>(cnt, row_ptr, N_NODE);                    \
    csr_scatter<<<eb, 256, 0, stream>>>(SRC, DST, EL, ER, cnt, edge_src,       \
                                        edge_pe, NEDGE)

    // Wh_ind pass #1: only its scalar projections are kept (el_ind, er_rev)
    gemm_proj<<<N_NODE, 128, 0, stream>>>(feat_drug, W_ind, b_ind,
                                          a_ind, a_rev + D, Wh, el_ind, er_rev);
    // Wh_rev: kept in Wh for phase 1; also el_rev, er_ind
    gemm_proj<<<N_NODE, 128, 0, stream>>>(feat_disease, W_rev, b_rev,
                                          a_rev, a_ind + D, Wh, el_rev, er_ind);

    // ---- phase 1: h_drug <- rev_indication (messages = Wh_rev) ----
    BUILD_CSR(src_rev, dst_rev, el_rev, er_rev);
    csr_gather<<<gb, 256, 0, stream>>>(row_ptr, edge_src, edge_pe, Wh,
                                       out, N_NODE, 0);

    // Wh_ind pass #2: materialize Wh_ind (el_ind/er_rev recomputed, harmless)
    gemm_proj<<<N_NODE, 128, 0, stream>>>(feat_drug, W_ind, b_ind,
                                          a_ind, a_rev + D, Wh, el_ind, er_rev);

    // ---- phase 2a: h_disease partial <- indication (messages = Wh_ind) ----
    BUILD_CSR(src_ind, dst_ind, el_ind, er_ind);
    csr_gather<<<gb, 256, 0, stream>>>(row_ptr, edge_src, edge_pe, Wh,
                                       out + hn, N_NODE, 0);

    // Wh_dd
    gemm_proj<<<N_NODE, 128, 0, stream>>>(feat_disease, W_dd, b_dd,
                                          a_dd, a_dd + D, Wh, el_dd, er_dd);

    // ---- phase 2b: h_disease += disease_disease (messages = Wh_dd) ----
    BUILD_CSR(src_dd, dst_dd, el_dd, er_dd);
    csr_gather<<<gb, 256, 0, stream>>>(row_ptr, edge_src, edge_pe, Wh,
                                       out + hn, N_NODE, 1);
#undef BUILD_CSR
}

// Round 5
// 492.589 us; speedup vs baseline: 1.2103x; 1.2103x over previous
//
#include <hip/hip_runtime.h>
#include <hip/hip_bf16.h>

typedef __hip_bfloat16 bf16;

#define N_NODE 20000
#define D      128
#define NEDGE  300000

// ---------------------------------------------------------------- fill
__global__ void fill_i32(int* __restrict__ p, int v, int n) {
    int i = blockIdx.x * blockDim.x + threadIdx.x;
    int stride = gridDim.x * blockDim.x;
    for (; i < n; i += stride) p[i] = v;
}

// ---------------------------------------------------------------- GEMM + projections (v2)
// 8 nodes per block of 128 threads; thread j owns output col j for all 8.
// feat row reads are wave-uniform (node from blockIdx) -> s_load path; each
// W[k][j] load is amortized over 8 independent FMA chains (breaks the round-4
// serial-accumulator latency chain: 12 VGPRs / VALUBusy 24% -> 8 accums).
__global__ __launch_bounds__(128) void gemm_proj8(
    const float* __restrict__ feat, const float* __restrict__ W,
    const float* __restrict__ bias, const float* __restrict__ va,
    const float* __restrict__ vb, bf16* __restrict__ Wh,
    float* __restrict__ el, float* __restrict__ er) {
    __shared__ float redA[2][8];
    __shared__ float redB[2][8];
    const int j = threadIdx.x;            // column 0..127
    const int n0 = blockIdx.x * 8;        // first node of this block
    const float vaj = va[j];
    const float vbj = vb[j];
    const float bj  = bias[j];
    const float* fr = feat + (size_t)n0 * D;

    float acc[8];
#pragma unroll
    for (int n = 0; n < 8; ++n) acc[n] = bj;

    for (int k = 0; k < D; k += 4) {
        const float w0 = W[(k + 0) * D + j];
        const float w1 = W[(k + 1) * D + j];
        const float w2 = W[(k + 2) * D + j];
        const float w3 = W[(k + 3) * D + j];
#pragma unroll
        for (int n = 0; n < 8; ++n) {
            const float4 f = *(const float4*)(fr + n * D + k);  // uniform -> s_load
            acc[n] = fmaf(f.x, w0, acc[n]);
            acc[n] = fmaf(f.y, w1, acc[n]);
            acc[n] = fmaf(f.z, w2, acc[n]);
            acc[n] = fmaf(f.w, w3, acc[n]);
        }
    }

    const int wave = j >> 6, lane = j & 63;
#pragma unroll
    for (int n = 0; n < 8; ++n) {
        const float a = acc[n];
        Wh[(size_t)(n0 + n) * D + j] = __float2bfloat16(a);
        float ea = a * vaj;
        float eb = a * vbj;
#pragma unroll
        for (int off = 32; off > 0; off >>= 1) {
            ea += __shfl_down(ea, off, 64);
            eb += __shfl_down(eb, off, 64);
        }
        if (lane == 0) { redA[wave][n] = ea; redB[wave][n] = eb; }
    }
    __syncthreads();
    if (j < 8)       el[n0 + j]     = redA[0][j] + redA[1][j];
    else if (j < 16) er[n0 + j - 8] = redB[0][j - 8] + redB[1][j - 8];
}

// ---------------------------------------------------------------- CSR build
__global__ __launch_bounds__(256) void hist_dst(
    const int* __restrict__ dst, int* __restrict__ cnt, int E) {
    int i = blockIdx.x * blockDim.x + threadIdx.x;
    int stride = gridDim.x * blockDim.x;
    for (; i < E; i += stride) atomicAdd(&cnt[dst[i]], 1);
}

// hierarchical scan, stage 1: per-block (256) exclusive scan + block total
__global__ __launch_bounds__(256) void scan_local(
    const int* __restrict__ cnt, int* __restrict__ partial,
    int* __restrict__ block_sums, int n) {
    __shared__ int wsum[4];
    const int idx = blockIdx.x * 256 + threadIdx.x;
    const int lane = threadIdx.x & 63, wave = threadIdx.x >> 6;
    int v = (idx < n) ? cnt[idx] : 0;
    const int orig = v;
#pragma unroll
    for (int off = 1; off < 64; off <<= 1) {
        int t = __shfl_up(v, off, 64);
        if (lane >= off) v += t;
    }
    if (lane == 63) wsum[wave] = v;
    __syncthreads();
    if (threadIdx.x == 0) {
        int a = 0;
#pragma unroll
        for (int w = 0; w < 4; ++w) { int t = wsum[w]; wsum[w] = a; a += t; }
    }
    __syncthreads();
    const int incl = wsum[wave] + v;
    if (idx < n) partial[idx] = incl - orig;   // exclusive within block
    if (threadIdx.x == 255) block_sums[blockIdx.x] = incl;
}

// stage 2: single wave scans the block totals (exclusive, in place)
__global__ __launch_bounds__(64) void scan_tops(int* __restrict__ bs, int nb) {
    const int lane = threadIdx.x;
    int carry = 0;
    for (int base = 0; base < nb; base += 64) {
        int v = (base + lane < nb) ? bs[base + lane] : 0;
        const int orig = v;
#pragma unroll
        for (int off = 1; off < 64; off <<= 1) {
            int t = __shfl_up(v, off, 64);
            if (lane >= off) v += t;
        }
        if (base + lane < nb) bs[base + lane] = carry + v - orig;
        carry += __shfl(v, 63, 64);
    }
}

// stage 3: add block offsets; write row_ptr AND cursor (folds the old copy)
__global__ __launch_bounds__(256) void scan_add(
    const int* __restrict__ partial, const int* __restrict__ block_sums,
    int* __restrict__ row_ptr, int* __restrict__ cursor, int n, int total) {
    const int idx = blockIdx.x * 256 + threadIdx.x;
    if (idx < n) {
        const int r = partial[idx] + block_sums[blockIdx.x];
        row_ptr[idx] = r;
        cursor[idx] = r;
    }
    if (idx == 0) row_ptr[n] = total;
}

// scatter edges into dst-sorted slots; also accumulate segment-sum s[d].
// No max-subtraction: softmax is shift-invariant and |e| <= ~3 here, so exp
// stays comfortably inside f32 range — same math as the reference.
__global__ __launch_bounds__(256) void csr_scatter(
    const int* __restrict__ src, const int* __restrict__ dst,
    const float* __restrict__ el, const float* __restrict__ er,
    int* __restrict__ cursor, int* __restrict__ edge_src,
    float* __restrict__ edge_pe, float* __restrict__ s, int E) {
    int i = blockIdx.x * blockDim.x + threadIdx.x;
    int stride = gridDim.x * blockDim.x;
    for (; i < E; i += stride) {
        const int sr = src[i];
        const int d = dst[i];
        float v = el[sr] + er[d];
        v = v > 0.f ? v : 0.01f * v;
        const float pe = expf(v);
        const int slot = atomicAdd(&cursor[d], 1);
        edge_src[slot] = sr;
        edge_pe[slot] = pe;
        atomicAdd(&s[d], pe);
    }
}

// ---------------------------------------------------------------- gather
// One wave per dst node; lane l owns output cols {2l, 2l+1}. Segment sum s
// comes precomputed from csr_scatter (old pass 1 deleted). Edge loop is
// unrolled x2 so the two row-gathers are in flight together.
__global__ __launch_bounds__(256) void csr_gather(
    const int* __restrict__ row_ptr, const int* __restrict__ edge_src,
    const float* __restrict__ edge_pe, const float* __restrict__ s,
    const bf16* __restrict__ Wh, float* __restrict__ out, int n, int accumulate) {
    const int node = blockIdx.x * (blockDim.x >> 6) + (threadIdx.x >> 6);
    const int lane = threadIdx.x & 63;
    if (node >= n) return;
    const int beg = row_ptr[node];
    const int end = row_ptr[node + 1];
    const float inv = (end > beg) ? 1.0f / s[node] : 0.f;

    float2* outv = (float2*)(out + (size_t)node * D) + lane;
    float a0 = 0.f, a1 = 0.f;
    if (accumulate) {
        const float2 prev = *outv;
        a0 = prev.x; a1 = prev.y;
    }
    int i = beg;
    for (; i + 1 < end; i += 2) {
        const int s0 = edge_src[i], s1 = edge_src[i + 1];
        const float c0 = edge_pe[i] * inv, c1 = edge_pe[i + 1] * inv;
        const unsigned u0 = ((const unsigned*)(Wh + (size_t)s0 * D))[lane];
        const unsigned u1 = ((const unsigned*)(Wh + (size_t)s1 * D))[lane];
        a0 = fmaf(c0, __uint_as_float(u0 << 16), a0);
        a1 = fmaf(c0, __uint_as_float(u0 & 0xFFFF0000u), a1);
        a0 = fmaf(c1, __uint_as_float(u1 << 16), a0);
        a1 = fmaf(c1, __uint_as_float(u1 & 0xFFFF0000u), a1);
    }
    if (i < end) {
        const float c0 = edge_pe[i] * inv;
        const unsigned u0 = ((const unsigned*)(Wh + (size_t)edge_src[i] * D))[lane];
        a0 = fmaf(c0, __uint_as_float(u0 << 16), a0);
        a1 = fmaf(c0, __uint_as_float(u0 & 0xFFFF0000u), a1);
    }
    *outv = make_float2(a0, a1);
}

extern "C" void kernel_launch(void* const* d_in, const int* in_sizes, int n_in,
                              void* d_out, int out_size, void* d_ws, size_t ws_size,
                              hipStream_t stream) {
    const float* feat_drug    = (const float*)d_in[0];
    const float* feat_disease = (const float*)d_in[1];
    const float* W_ind = (const float*)d_in[2];
    const float* b_ind = (const float*)d_in[3];
    const float* a_ind = (const float*)d_in[4];
    const float* W_rev = (const float*)d_in[5];
    const float* b_rev = (const float*)d_in[6];
    const float* a_rev = (const float*)d_in[7];
    const float* W_dd  = (const float*)d_in[8];
    const float* b_dd  = (const float*)d_in[9];
    const float* a_dd  = (const float*)d_in[10];
    const int* src_ind = (const int*)d_in[11];
    const int* dst_ind = (const int*)d_in[12];
    const int* src_rev = (const int*)d_in[13];
    const int* dst_rev = (const int*)d_in[14];
    const int* src_dd  = (const int*)d_in[15];
    const int* dst_dd  = (const int*)d_in[16];
    float* out = (float*)d_out;
    (void)in_sizes; (void)n_in; (void)out_size; (void)ws_size;

    // ---- workspace: ~8.24 MB ----
    char* w = (char*)d_ws;
    bf16*  Wh       = (bf16*)w;                    // 5,120,000 B (shared)
    float* el_ind   = (float*)(w + 5120000);       // 6 x 80,000 B
    float* er_ind   = (float*)(w + 5200000);
    float* el_rev   = (float*)(w + 5280000);
    float* er_rev   = (float*)(w + 5360000);
    float* el_dd    = (float*)(w + 5440000);
    float* er_dd    = (float*)(w + 5520000);
    int*   row_ptr  = (int*)(w + 5600000);         // 80,004 B (pad to 80,032)
    int*   cnt      = (int*)(w + 5680032);         // 80,000 B (becomes cursor)
    float* s        = (float*)(w + 5760032);       // 80,000 B (adjacent to cnt)
    int*   bsums    = (int*)(w + 5840032);         // 512 B
    int*   edge_src = (int*)(w + 5840544);         // 1,200,000 B (stage-1 also
    float* edge_pe  = (float*)(w + 7040544);       //   aliases scan 'partial')
    int*   partial  = edge_src;                    // alias: dead before scatter

    const int hn = N_NODE * D;
    const int eb = (NEDGE + 255) / 256;
    const int nb = (N_NODE + 255) / 256;           // 79 blocks
    const int gb = (N_NODE + 3) / 4;               // gather: 4 waves/block

#define BUILD_AND_GATHER(SRC, DST, EL, ER, OUT, ACC)                            \
    fill_i32<<<157, 256, 0, stream>>>(cnt, 0, 2 * N_NODE);  /* cnt + s */       \
    hist_dst<<<eb, 256, 0, stream>>>(DST, cnt, NEDGE);                          \
    scan_local<<<nb, 256, 0, stream>>>(cnt, partial, bsums, N_NODE);            \
    scan_tops<<<1, 64, 0, stream>>>(bsums, nb);                                 \
    scan_add<<<nb, 256, 0, stream>>>(partial, bsums, row_ptr, cnt, N_NODE,      \
                                     NEDGE);                                    \
    csr_scatter<<<eb, 256, 0, stream>>>(SRC, DST, EL, ER, cnt, edge_src,        \
                                        edge_pe, s, NEDGE);                     \
    csr_gather<<<gb, 256, 0, stream>>>(row_ptr, edge_src, edge_pe, s, Wh,       \
                                       OUT, N_NODE, ACC)

    // projections first (Wh of pass-1 ind is overwritten, only el/er kept)
    gemm_proj8<<<N_NODE / 8, 128, 0, stream>>>(feat_drug, W_ind, b_ind,
                                               a_ind, a_rev + D, Wh, el_ind, er_rev);
    gemm_proj8<<<N_NODE / 8, 128, 0, stream>>>(feat_disease, W_rev, b_rev,
                                               a_rev, a_ind + D, Wh, el_rev, er_ind);

    // phase 1: h_drug <- rev_indication (messages = Wh_rev, currently in Wh)
    BUILD_AND_GATHER(src_rev, dst_rev, el_rev, er_rev, out, 0);

    // rematerialize Wh_ind
    gemm_proj8<<<N_NODE / 8, 128, 0, stream>>>(feat_drug, W_ind, b_ind,
                                               a_ind, a_rev + D, Wh, el_ind, er_rev);
    // phase 2a: h_disease <- indication
    BUILD_AND_GATHER(src_ind, dst_ind, el_ind, er_ind, out + hn, 0);

    // Wh_dd
    gemm_proj8<<<N_NODE / 8, 128, 0, stream>>>(feat_disease, W_dd, b_dd,
                                               a_dd, a_dd + D, Wh, el_dd, er_dd);
    // phase 2b: h_disease += disease_disease
    BUILD_AND_GATHER(src_dd, dst_dd, el_dd, er_dd, out + hn, 1);
#undef BUILD_AND_GATHER
}

// Round 6
// 418.638 us; speedup vs baseline: 1.4241x; 1.1766x over previous
//
#include <hip/hip_runtime.h>
#include <hip/hip_bf16.h>

typedef __hip_bfloat16 bf16;

#define N_NODE 20000
#define D      128
#define NEDGE  300000

// ---------------------------------------------------------------- fill
__global__ void fill_i32(int* __restrict__ p, int v, int n) {
    int i = blockIdx.x * blockDim.x + threadIdx.x;
    int stride = gridDim.x * blockDim.x;
    for (; i < n; i += stride) p[i] = v;
}

// ---------------------------------------------------------------- GEMM + projections (v3)
// 8 nodes per block of 128 threads; thread j owns output col j for all 8.
// v2 lesson: per-lane "uniform" float4 feat loads are NOT scalarized -> 12
// VMEM ops/k-step -> vmcnt-wait latency-bound (VALUBusy 9.5%). v3 stages the
// 8 feat rows in LDS once (coalesced), so the k-loop does only 4 coalesced
// W loads (L2-hot) + broadcast ds_reads + 32 FMAs.
__global__ __launch_bounds__(128) void gemm_proj8(
    const float* __restrict__ feat, const float* __restrict__ W,
    const float* __restrict__ bias, const float* __restrict__ va,
    const float* __restrict__ vb, bf16* __restrict__ Wh,
    float* __restrict__ el, float* __restrict__ er) {
    __shared__ float fs[8 * D];           // 4 KB
    __shared__ float redA[2][8];
    __shared__ float redB[2][8];
    const int j = threadIdx.x;            // column 0..127
    const int n0 = blockIdx.x * 8;        // first node of this block

    // cooperative stage: 8 rows x 128 f32 = 256 float4; 2 per thread
    {
        const float4* srcv = (const float4*)(feat + (size_t)n0 * D);
        float4* dstv = (float4*)fs;
        dstv[j] = srcv[j];
        dstv[j + 128] = srcv[j + 128];
    }
    const float vaj = va[j];
    const float vbj = vb[j];
    const float bj  = bias[j];
    __syncthreads();

    float acc[8];
#pragma unroll
    for (int n = 0; n < 8; ++n) acc[n] = bj;

    for (int k = 0; k < D; k += 4) {
        const float w0 = W[(k + 0) * D + j];
        const float w1 = W[(k + 1) * D + j];
        const float w2 = W[(k + 2) * D + j];
        const float w3 = W[(k + 3) * D + j];
        float4 f[8];
#pragma unroll
        for (int n = 0; n < 8; ++n) f[n] = *(const float4*)(fs + n * D + k);
#pragma unroll
        for (int n = 0; n < 8; ++n) {
            acc[n] = fmaf(f[n].x, w0, acc[n]);
            acc[n] = fmaf(f[n].y, w1, acc[n]);
            acc[n] = fmaf(f[n].z, w2, acc[n]);
            acc[n] = fmaf(f[n].w, w3, acc[n]);
        }
    }

    const int wave = j >> 6, lane = j & 63;
#pragma unroll
    for (int n = 0; n < 8; ++n) {
        const float a = acc[n];
        Wh[(size_t)(n0 + n) * D + j] = __float2bfloat16(a);
        float ea = a * vaj;
        float eb = a * vbj;
#pragma unroll
        for (int off = 32; off > 0; off >>= 1) {
            ea += __shfl_down(ea, off, 64);
            eb += __shfl_down(eb, off, 64);
        }
        if (lane == 0) { redA[wave][n] = ea; redB[wave][n] = eb; }
    }
    __syncthreads();
    if (j < 8)       el[n0 + j]     = redA[0][j] + redA[1][j];
    else if (j < 16) er[n0 + j - 8] = redB[0][j - 8] + redB[1][j - 8];
}

// ---------------------------------------------------------------- CSR build
__global__ __launch_bounds__(256) void hist_dst(
    const int* __restrict__ dst, int* __restrict__ cnt, int E) {
    int i = blockIdx.x * blockDim.x + threadIdx.x;
    int stride = gridDim.x * blockDim.x;
    for (; i < E; i += stride) atomicAdd(&cnt[dst[i]], 1);
}

// hierarchical scan, stage 1: per-block (256) exclusive scan + block total
__global__ __launch_bounds__(256) void scan_local(
    const int* __restrict__ cnt, int* __restrict__ partial,
    int* __restrict__ block_sums, int n) {
    __shared__ int wsum[4];
    const int idx = blockIdx.x * 256 + threadIdx.x;
    const int lane = threadIdx.x & 63, wave = threadIdx.x >> 6;
    int v = (idx < n) ? cnt[idx] : 0;
    const int orig = v;
#pragma unroll
    for (int off = 1; off < 64; off <<= 1) {
        int t = __shfl_up(v, off, 64);
        if (lane >= off) v += t;
    }
    if (lane == 63) wsum[wave] = v;
    __syncthreads();
    if (threadIdx.x == 0) {
        int a = 0;
#pragma unroll
        for (int w = 0; w < 4; ++w) { int t = wsum[w]; wsum[w] = a; a += t; }
    }
    __syncthreads();
    const int incl = wsum[wave] + v;
    if (idx < n) partial[idx] = incl - orig;   // exclusive within block
    if (threadIdx.x == 255) block_sums[blockIdx.x] = incl;
}

// stage 2: single wave scans the block totals (exclusive, in place)
__global__ __launch_bounds__(64) void scan_tops(int* __restrict__ bs, int nb) {
    const int lane = threadIdx.x;
    int carry = 0;
    for (int base = 0; base < nb; base += 64) {
        int v = (base + lane < nb) ? bs[base + lane] : 0;
        const int orig = v;
#pragma unroll
        for (int off = 1; off < 64; off <<= 1) {
            int t = __shfl_up(v, off, 64);
            if (lane >= off) v += t;
        }
        if (base + lane < nb) bs[base + lane] = carry + v - orig;
        carry += __shfl(v, 63, 64);
    }
}

// stage 3: add block offsets; write row_ptr + cursor + zero the segment sums
__global__ __launch_bounds__(256) void scan_add(
    const int* __restrict__ partial, const int* __restrict__ block_sums,
    int* __restrict__ row_ptr, int* __restrict__ cursor,
    float* __restrict__ s, int n, int total) {
    const int idx = blockIdx.x * 256 + threadIdx.x;
    if (idx < n) {
        const int r = partial[idx] + block_sums[blockIdx.x];
        row_ptr[idx] = r;
        cursor[idx] = r;
        s[idx] = 0.f;
    }
    if (idx == 0) row_ptr[n] = total;
}

// scatter edges into dst-sorted slots; also accumulate segment-sum s[d].
// No max-subtraction: softmax is shift-invariant and |e| <= ~3 here, so exp
// stays comfortably inside f32 range — same math as the reference.
__global__ __launch_bounds__(256) void csr_scatter(
    const int* __restrict__ src, const int* __restrict__ dst,
    const float* __restrict__ el, const float* __restrict__ er,
    int* __restrict__ cursor, int* __restrict__ edge_src,
    float* __restrict__ edge_pe, float* __restrict__ s, int E) {
    int i = blockIdx.x * blockDim.x + threadIdx.x;
    int stride = gridDim.x * blockDim.x;
    for (; i < E; i += stride) {
        const int sr = src[i];
        const int d = dst[i];
        float v = el[sr] + er[d];
        v = v > 0.f ? v : 0.01f * v;
        const float pe = expf(v);
        const int slot = atomicAdd(&cursor[d], 1);
        edge_src[slot] = sr;
        edge_pe[slot] = pe;
        atomicAdd(&s[d], pe);
    }
}

// ---------------------------------------------------------------- gather (v2)
// One wave per dst node; lane l owns output cols {2l, 2l+1}.
// v1 lesson: per-edge dependent loads (edge_src -> Wh row) serialize ~500cyc
// per edge-pair. v2: lane l preloads edge meta [beg+l] in ONE coalesced load,
// wave iterates edges via shfl broadcast (register-speed), Wh gathers
// unrolled x4 so 4 independent row-loads are in flight.
__global__ __launch_bounds__(256) void csr_gather(
    const int* __restrict__ row_ptr, const int* __restrict__ edge_src,
    const float* __restrict__ edge_pe, const float* __restrict__ s,
    const bf16* __restrict__ Wh, float* __restrict__ out, int n, int accumulate) {
    const int node = blockIdx.x * (blockDim.x >> 6) + (threadIdx.x >> 6);
    const int lane = threadIdx.x & 63;
    if (node >= n) return;
    const int beg = row_ptr[node];
    const int end = row_ptr[node + 1];
    const float inv = (end > beg) ? 1.0f / s[node] : 0.f;

    float2* outv = (float2*)(out + (size_t)node * D) + lane;
    float a0 = 0.f, a1 = 0.f;
    if (accumulate) {
        const float2 prev = *outv;
        a0 = prev.x; a1 = prev.y;
    }

    for (int base = beg; base < end; base += 64) {
        const int m = min(end - base, 64);
        int msrc = 0; float mpe = 0.f;
        if (lane < m) {
            msrc = edge_src[base + lane];
            mpe  = edge_pe[base + lane];
        }
        int t = 0;
        for (; t + 4 <= m; t += 4) {
            const int s0 = __shfl(msrc, t,     64);
            const int s1 = __shfl(msrc, t + 1, 64);
            const int s2 = __shfl(msrc, t + 2, 64);
            const int s3 = __shfl(msrc, t + 3, 64);
            const float c0 = __shfl(mpe, t,     64) * inv;
            const float c1 = __shfl(mpe, t + 1, 64) * inv;
            const float c2 = __shfl(mpe, t + 2, 64) * inv;
            const float c3 = __shfl(mpe, t + 3, 64) * inv;
            const unsigned u0 = ((const unsigned*)(Wh + (size_t)s0 * D))[lane];
            const unsigned u1 = ((const unsigned*)(Wh + (size_t)s1 * D))[lane];
            const unsigned u2 = ((const unsigned*)(Wh + (size_t)s2 * D))[lane];
            const unsigned u3 = ((const unsigned*)(Wh + (size_t)s3 * D))[lane];
            a0 = fmaf(c0, __uint_as_float(u0 << 16), a0);
            a1 = fmaf(c0, __uint_as_float(u0 & 0xFFFF0000u), a1);
            a0 = fmaf(c1, __uint_as_float(u1 << 16), a0);
            a1 = fmaf(c1, __uint_as_float(u1 & 0xFFFF0000u), a1);
            a0 = fmaf(c2, __uint_as_float(u2 << 16), a0);
            a1 = fmaf(c2, __uint_as_float(u2 & 0xFFFF0000u), a1);
            a0 = fmaf(c3, __uint_as_float(u3 << 16), a0);
            a1 = fmaf(c3, __uint_as_float(u3 & 0xFFFF0000u), a1);
        }
        for (; t < m; ++t) {
            const int s0 = __shfl(msrc, t, 64);
            const float c0 = __shfl(mpe, t, 64) * inv;
            const unsigned u0 = ((const unsigned*)(Wh + (size_t)s0 * D))[lane];
            a0 = fmaf(c0, __uint_as_float(u0 << 16), a0);
            a1 = fmaf(c0, __uint_as_float(u0 & 0xFFFF0000u), a1);
        }
    }
    *outv = make_float2(a0, a1);
}

extern "C" void kernel_launch(void* const* d_in, const int* in_sizes, int n_in,
                              void* d_out, int out_size, void* d_ws, size_t ws_size,
                              hipStream_t stream) {
    const float* feat_drug    = (const float*)d_in[0];
    const float* feat_disease = (const float*)d_in[1];
    const float* W_ind = (const float*)d_in[2];
    const float* b_ind = (const float*)d_in[3];
    const float* a_ind = (const float*)d_in[4];
    const float* W_rev = (const float*)d_in[5];
    const float* b_rev = (const float*)d_in[6];
    const float* a_rev = (const float*)d_in[7];
    const float* W_dd  = (const float*)d_in[8];
    const float* b_dd  = (const float*)d_in[9];
    const float* a_dd  = (const float*)d_in[10];
    const int* src_ind = (const int*)d_in[11];
    const int* dst_ind = (const int*)d_in[12];
    const int* src_rev = (const int*)d_in[13];
    const int* dst_rev = (const int*)d_in[14];
    const int* src_dd  = (const int*)d_in[15];
    const int* dst_dd  = (const int*)d_in[16];
    float* out = (float*)d_out;
    (void)in_sizes; (void)n_in; (void)out_size; (void)ws_size;

    // ---- workspace: ~8.24 MB ----
    char* w = (char*)d_ws;
    bf16*  Wh       = (bf16*)w;                    // 5,120,000 B (shared)
    float* el_ind   = (float*)(w + 5120000);       // 6 x 80,000 B
    float* er_ind   = (float*)(w + 5200000);
    float* el_rev   = (float*)(w + 5280000);
    float* er_rev   = (float*)(w + 5360000);
    float* el_dd    = (float*)(w + 5440000);
    float* er_dd    = (float*)(w + 5520000);
    int*   row_ptr  = (int*)(w + 5600000);         // 80,004 B (pad to 80,032)
    int*   cnt      = (int*)(w + 5680032);         // 80,000 B (becomes cursor)
    float* s        = (float*)(w + 5760032);       // 80,000 B
    int*   bsums    = (int*)(w + 5840032);         // 512 B
    int*   edge_src = (int*)(w + 5840544);         // 1,200,000 B (stage-1 also
    float* edge_pe  = (float*)(w + 7040544);       //   aliases scan 'partial')
    int*   partial  = edge_src;                    // alias: dead before scatter

    const int hn = N_NODE * D;
    const int eb = (NEDGE + 255) / 256;
    const int nb = (N_NODE + 255) / 256;           // 79 blocks
    const int gb = (N_NODE + 3) / 4;               // gather: 4 waves/block

#define BUILD_AND_GATHER(SRC, DST, EL, ER, OUT, ACC)                            \
    fill_i32<<<nb, 256, 0, stream>>>(cnt, 0, N_NODE);                           \
    hist_dst<<<eb, 256, 0, stream>>>(DST, cnt, NEDGE);                          \
    scan_local<<<nb, 256, 0, stream>>>(cnt, partial, bsums, N_NODE);            \
    scan_tops<<<1, 64, 0, stream>>>(bsums, nb);                                 \
    scan_add<<<nb, 256, 0, stream>>>(partial, bsums, row_ptr, cnt, s, N_NODE,   \
                                     NEDGE);                                    \
    csr_scatter<<<eb, 256, 0, stream>>>(SRC, DST, EL, ER, cnt, edge_src,        \
                                        edge_pe, s, NEDGE);                     \
    csr_gather<<<gb, 256, 0, stream>>>(row_ptr, edge_src, edge_pe, s, Wh,       \
                                       OUT, N_NODE, ACC)

    // projections first (Wh of pass-1 ind is overwritten, only el/er kept)
    gemm_proj8<<<N_NODE / 8, 128, 0, stream>>>(feat_drug, W_ind, b_ind,
                                               a_ind, a_rev + D, Wh, el_ind, er_rev);
    gemm_proj8<<<N_NODE / 8, 128, 0, stream>>>(feat_disease, W_rev, b_rev,
                                               a_rev, a_ind + D, Wh, el_rev, er_ind);

    // phase 1: h_drug <- rev_indication (messages = Wh_rev, currently in Wh)
    BUILD_AND_GATHER(src_rev, dst_rev, el_rev, er_rev, out, 0);

    // rematerialize Wh_ind
    gemm_proj8<<<N_NODE / 8, 128, 0, stream>>>(feat_drug, W_ind, b_ind,
                                               a_ind, a_rev + D, Wh, el_ind, er_rev);
    // phase 2a: h_disease <- indication
    BUILD_AND_GATHER(src_ind, dst_ind, el_ind, er_ind, out + hn, 0);

    // Wh_dd
    gemm_proj8<<<N_NODE / 8, 128, 0, stream>>>(feat_disease, W_dd, b_dd,
                                               a_dd, a_dd + D, Wh, el_dd, er_dd);
    // phase 2b: h_disease += disease_disease
    BUILD_AND_GATHER(src_dd, dst_dd, el_dd, er_dd, out + hn, 1);
#undef BUILD_AND_GATHER
}

// Round 7
// 329.992 us; speedup vs baseline: 1.8067x; 1.2686x over previous
//
#include <hip/hip_runtime.h>
#include <hip/hip_bf16.h>

typedef __hip_bfloat16 bf16;

#define N_NODE 20000
#define D      128
#define NEDGE  300000
#define NROW   (3 * N_NODE)        // CSR rows: [rev | ind | dd] x dst-node
#define NBS    ((NROW + 255) / 256)  // scan blocks = 235

// ---------------------------------------------------------------- fill
__global__ void fill_i32(int* __restrict__ p, int v, int n) {
    int i = blockIdx.x * blockDim.x + threadIdx.x;
    int stride = gridDim.x * blockDim.x;
    for (; i < n; i += stride) p[i] = v;
}

// ---------------------------------------------------------------- fused GEMM + projections
// grid = 3*2500 blocks; t = etype of the GEMM (0=rev,1=ind,2=dd). 8 nodes per
// block of 128 threads; thread j owns col j. Feat rows staged via LDS
// (round-5 lesson: per-lane "uniform" float4 loads are not scalarized ->
// vmcnt-latency-bound). el/er cross-wiring:
//   t=0 computes Wh_rev -> el[rev] and er[ind] (Wh_rev . a_ind[D:])
//   t=1 computes Wh_ind -> el[ind] and er[rev] (Wh_ind . a_rev[D:])
//   t=2 computes Wh_dd  -> el[dd]  and er[dd]
__global__ __launch_bounds__(128) void gemm_proj_all(
    const float* __restrict__ feat_drug, const float* __restrict__ feat_dis,
    const float* __restrict__ W_ind, const float* __restrict__ b_ind,
    const float* __restrict__ a_ind,
    const float* __restrict__ W_rev, const float* __restrict__ b_rev,
    const float* __restrict__ a_rev,
    const float* __restrict__ W_dd, const float* __restrict__ b_dd,
    const float* __restrict__ a_dd,
    bf16* __restrict__ Wh_all, float* __restrict__ el_all,
    float* __restrict__ er_all) {
    __shared__ float fs[8 * D];           // 4 KB
    __shared__ float redA[2][8];
    __shared__ float redB[2][8];
    const int t = blockIdx.x / 2500;
    const int b = blockIdx.x - t * 2500;
    const int j = threadIdx.x;
    const int n0 = b * 8;

    const float *feat, *W, *bias, *va, *vb;
    float *el_o, *er_o;
    if (t == 0)      { feat = feat_dis;  W = W_rev; bias = b_rev; va = a_rev; vb = a_ind + D; el_o = el_all;              er_o = er_all + N_NODE; }
    else if (t == 1) { feat = feat_drug; W = W_ind; bias = b_ind; va = a_ind; vb = a_rev + D; el_o = el_all + N_NODE;     er_o = er_all; }
    else             { feat = feat_dis;  W = W_dd;  bias = b_dd;  va = a_dd;  vb = a_dd + D;  el_o = el_all + 2 * N_NODE; er_o = er_all + 2 * N_NODE; }
    bf16* wh_o = Wh_all + (size_t)t * N_NODE * D;

    {   // cooperative stage: 8 rows x 128 f32 = 256 float4; 2 per thread
        const float4* srcv = (const float4*)(feat + (size_t)n0 * D);
        float4* dstv = (float4*)fs;
        dstv[j] = srcv[j];
        dstv[j + 128] = srcv[j + 128];
    }
    const float vaj = va[j];
    const float vbj = vb[j];
    const float bj  = bias[j];
    __syncthreads();

    float acc[8];
#pragma unroll
    for (int n = 0; n < 8; ++n) acc[n] = bj;

    for (int k = 0; k < D; k += 4) {
        const float w0 = W[(k + 0) * D + j];
        const float w1 = W[(k + 1) * D + j];
        const float w2 = W[(k + 2) * D + j];
        const float w3 = W[(k + 3) * D + j];
        float4 f[8];
#pragma unroll
        for (int n = 0; n < 8; ++n) f[n] = *(const float4*)(fs + n * D + k);
#pragma unroll
        for (int n = 0; n < 8; ++n) {
            acc[n] = fmaf(f[n].x, w0, acc[n]);
            acc[n] = fmaf(f[n].y, w1, acc[n]);
            acc[n] = fmaf(f[n].z, w2, acc[n]);
            acc[n] = fmaf(f[n].w, w3, acc[n]);
        }
    }

    const int wave = j >> 6, lane = j & 63;
#pragma unroll
    for (int n = 0; n < 8; ++n) {
        const float a = acc[n];
        wh_o[(size_t)(n0 + n) * D + j] = __float2bfloat16(a);
        float ea = a * vaj;
        float eb = a * vbj;
#pragma unroll
        for (int off = 32; off > 0; off >>= 1) {
            ea += __shfl_down(ea, off, 64);
            eb += __shfl_down(eb, off, 64);
        }
        if (lane == 0) { redA[wave][n] = ea; redB[wave][n] = eb; }
    }
    __syncthreads();
    if (j < 8)       el_o[n0 + j]     = redA[0][j] + redA[1][j];
    else if (j < 16) er_o[n0 + j - 8] = redB[0][j - 8] + redB[1][j - 8];
}

// ---------------------------------------------------------------- CSR build (all etypes)
__global__ __launch_bounds__(256) void hist_all(
    const int* __restrict__ dst_rev, const int* __restrict__ dst_ind,
    const int* __restrict__ dst_dd, int* __restrict__ cnt) {
    int i = blockIdx.x * blockDim.x + threadIdx.x;
    int stride = gridDim.x * blockDim.x;
    for (; i < 3 * NEDGE; i += stride) {
        const int t = (i >= 2 * NEDGE) ? 2 : (i >= NEDGE ? 1 : 0);
        const int e = i - t * NEDGE;
        const int d = (t == 0 ? dst_rev : (t == 1 ? dst_ind : dst_dd))[e];
        atomicAdd(&cnt[t * N_NODE + d], 1);
    }
}

// hierarchical scan, stage 1: per-block (256) exclusive scan + block total
__global__ __launch_bounds__(256) void scan_local(
    const int* __restrict__ cnt, int* __restrict__ partial,
    int* __restrict__ block_sums, int n) {
    __shared__ int wsum[4];
    const int idx = blockIdx.x * 256 + threadIdx.x;
    const int lane = threadIdx.x & 63, wave = threadIdx.x >> 6;
    int v = (idx < n) ? cnt[idx] : 0;
    const int orig = v;
#pragma unroll
    for (int off = 1; off < 64; off <<= 1) {
        int t = __shfl_up(v, off, 64);
        if (lane >= off) v += t;
    }
    if (lane == 63) wsum[wave] = v;
    __syncthreads();
    if (threadIdx.x == 0) {
        int a = 0;
#pragma unroll
        for (int w = 0; w < 4; ++w) { int t = wsum[w]; wsum[w] = a; a += t; }
    }
    __syncthreads();
    const int incl = wsum[wave] + v;
    if (idx < n) partial[idx] = incl - orig;   // exclusive within block
    if (threadIdx.x == 255) block_sums[blockIdx.x] = incl;
}

// stage 2: single wave scans the block totals (exclusive, in place)
__global__ __launch_bounds__(64) void scan_tops(int* __restrict__ bs, int nb) {
    const int lane = threadIdx.x;
    int carry = 0;
    for (int base = 0; base < nb; base += 64) {
        int v = (base + lane < nb) ? bs[base + lane] : 0;
        const int orig = v;
#pragma unroll
        for (int off = 1; off < 64; off <<= 1) {
            int t = __shfl_up(v, off, 64);
            if (lane >= off) v += t;
        }
        if (base + lane < nb) bs[base + lane] = carry + v - orig;
        carry += __shfl(v, 63, 64);
    }
}

// stage 3: add block offsets; write row_ptr + cursor + zero segment sums
__global__ __launch_bounds__(256) void scan_add(
    const int* __restrict__ partial, const int* __restrict__ block_sums,
    int* __restrict__ row_ptr, int* __restrict__ cursor,
    float* __restrict__ s, int n, int total) {
    const int idx = blockIdx.x * 256 + threadIdx.x;
    if (idx < n) {
        const int r = partial[idx] + block_sums[blockIdx.x];
        row_ptr[idx] = r;
        cursor[idx] = r;
        s[idx] = 0.f;
    }
    if (idx == 0) row_ptr[n] = total;
}

// fused scatter over all 3 edge lists. Stores edge meta packed int2
// (global Wh row = t*N+src, pe bits) and accumulates segment-sum s[row].
// No max-subtraction: softmax is shift-invariant and |e| <= ~3, exp safe.
__global__ __launch_bounds__(256) void scatter_all(
    const int* __restrict__ src_rev, const int* __restrict__ dst_rev,
    const int* __restrict__ src_ind, const int* __restrict__ dst_ind,
    const int* __restrict__ src_dd,  const int* __restrict__ dst_dd,
    const float* __restrict__ el_all, const float* __restrict__ er_all,
    int* __restrict__ cursor, int2* __restrict__ edge_meta,
    float* __restrict__ s) {
    int i = blockIdx.x * blockDim.x + threadIdx.x;
    int stride = gridDim.x * blockDim.x;
    for (; i < 3 * NEDGE; i += stride) {
        const int t = (i >= 2 * NEDGE) ? 2 : (i >= NEDGE ? 1 : 0);
        const int e = i - t * NEDGE;
        const int sl = (t == 0 ? src_rev : (t == 1 ? src_ind : src_dd))[e];
        const int dl = (t == 0 ? dst_rev : (t == 1 ? dst_ind : dst_dd))[e];
        const int row = t * N_NODE + dl;
        float v = el_all[t * N_NODE + sl] + er_all[row];
        v = v > 0.f ? v : 0.01f * v;
        const float pe = expf(v);
        const int slot = atomicAdd(&cursor[row], 1);
        edge_meta[slot] = make_int2(t * N_NODE + sl, __float_as_int(pe));
        atomicAdd(&s[row], pe);
    }
}

// ---------------------------------------------------------------- gather
// Lane l preloads edge meta [base+l] in one coalesced 8B load; wave iterates
// edges via shfl broadcast; Wh row-gathers unrolled x4 for load ILP.
__device__ __forceinline__ void acc_range(
    const int2* __restrict__ edge_meta, const bf16* __restrict__ Wh_all,
    int beg, int end, float inv, int lane, float& a0, float& a1) {
    for (int base = beg; base < end; base += 64) {
        const int m = min(end - base, 64);
        int msrc = 0; float mpe = 0.f;
        if (lane < m) {
            const int2 em = edge_meta[base + lane];
            msrc = em.x; mpe = __int_as_float(em.y);
        }
        int t = 0;
        for (; t + 4 <= m; t += 4) {
            const int s0 = __shfl(msrc, t,     64);
            const int s1 = __shfl(msrc, t + 1, 64);
            const int s2 = __shfl(msrc, t + 2, 64);
            const int s3 = __shfl(msrc, t + 3, 64);
            const float c0 = __shfl(mpe, t,     64) * inv;
            const float c1 = __shfl(mpe, t + 1, 64) * inv;
            const float c2 = __shfl(mpe, t + 2, 64) * inv;
            const float c3 = __shfl(mpe, t + 3, 64) * inv;
            const unsigned u0 = ((const unsigned*)(Wh_all + (size_t)s0 * D))[lane];
            const unsigned u1 = ((const unsigned*)(Wh_all + (size_t)s1 * D))[lane];
            const unsigned u2 = ((const unsigned*)(Wh_all + (size_t)s2 * D))[lane];
            const unsigned u3 = ((const unsigned*)(Wh_all + (size_t)s3 * D))[lane];
            a0 = fmaf(c0, __uint_as_float(u0 << 16), a0);
            a1 = fmaf(c0, __uint_as_float(u0 & 0xFFFF0000u), a1);
            a0 = fmaf(c1, __uint_as_float(u1 << 16), a0);
            a1 = fmaf(c1, __uint_as_float(u1 & 0xFFFF0000u), a1);
            a0 = fmaf(c2, __uint_as_float(u2 << 16), a0);
            a1 = fmaf(c2, __uint_as_float(u2 & 0xFFFF0000u), a1);
            a0 = fmaf(c3, __uint_as_float(u3 << 16), a0);
            a1 = fmaf(c3, __uint_as_float(u3 & 0xFFFF0000u), a1);
        }
        for (; t < m; ++t) {
            const int s0 = __shfl(msrc, t, 64);
            const float c0 = __shfl(mpe, t, 64) * inv;
            const unsigned u0 = ((const unsigned*)(Wh_all + (size_t)s0 * D))[lane];
            a0 = fmaf(c0, __uint_as_float(u0 << 16), a0);
            a1 = fmaf(c0, __uint_as_float(u0 & 0xFFFF0000u), a1);
        }
    }
}

// One wave per OUTPUT row w in [0,40000): w<20000 -> h_drug row (CSR row w,
// etype rev); w>=20000 -> h_disease row (CSR rows w [ind] and w+20000 [dd],
// each with its own softmax normalizer). Single f32x2 store per lane.
__global__ __launch_bounds__(256) void gather_all(
    const int* __restrict__ row_ptr, const int2* __restrict__ edge_meta,
    const float* __restrict__ s, const bf16* __restrict__ Wh_all,
    float* __restrict__ out) {
    const int w = blockIdx.x * (blockDim.x >> 6) + (threadIdx.x >> 6);
    const int lane = threadIdx.x & 63;
    if (w >= 2 * N_NODE) return;

    float a0 = 0.f, a1 = 0.f;
    {
        const int beg = row_ptr[w], end = row_ptr[w + 1];
        const float inv = (end > beg) ? 1.0f / s[w] : 0.f;
        acc_range(edge_meta, Wh_all, beg, end, inv, lane, a0, a1);
    }
    if (w >= N_NODE) {   // disease row: add the disease_disease contribution
        const int r = w + N_NODE;
        const int beg = row_ptr[r], end = row_ptr[r + 1];
        const float inv = (end > beg) ? 1.0f / s[r] : 0.f;
        acc_range(edge_meta, Wh_all, beg, end, inv, lane, a0, a1);
    }
    ((float2*)(out + (size_t)w * D))[lane] = make_float2(a0, a1);
}

extern "C" void kernel_launch(void* const* d_in, const int* in_sizes, int n_in,
                              void* d_out, int out_size, void* d_ws, size_t ws_size,
                              hipStream_t stream) {
    const float* feat_drug    = (const float*)d_in[0];
    const float* feat_disease = (const float*)d_in[1];
    const float* W_ind = (const float*)d_in[2];
    const float* b_ind = (const float*)d_in[3];
    const float* a_ind = (const float*)d_in[4];
    const float* W_rev = (const float*)d_in[5];
    const float* b_rev = (const float*)d_in[6];
    const float* a_rev = (const float*)d_in[7];
    const float* W_dd  = (const float*)d_in[8];
    const float* b_dd  = (const float*)d_in[9];
    const float* a_dd  = (const float*)d_in[10];
    const int* src_ind = (const int*)d_in[11];
    const int* dst_ind = (const int*)d_in[12];
    const int* src_rev = (const int*)d_in[13];
    const int* dst_rev = (const int*)d_in[14];
    const int* src_dd  = (const int*)d_in[15];
    const int* dst_dd  = (const int*)d_in[16];
    float* out = (float*)d_out;
    (void)in_sizes; (void)n_in; (void)out_size; (void)ws_size;

    // ---- workspace: ~23.8 MB (ws is ~256 MB per round-6 fill counters) ----
    char* w = (char*)d_ws;
    bf16*  Wh_all    = (bf16*)w;                    // 15,360,000 B  [rev|ind|dd]
    float* el_all    = (float*)(w + 15360000);      // 240,000 B
    float* er_all    = (float*)(w + 15600000);      // 240,000 B
    int*   row_ptr   = (int*)(w + 15840000);        // 240,004 -> pad 240,032
    int*   cnt       = (int*)(w + 16080032);        // 240,000 B (becomes cursor)
    float* s         = (float*)(w + 16320032);      // 240,000 B
    int*   bsums     = (int*)(w + 16560032);        // 1,024 B
    int2*  edge_meta = (int2*)(w + 16561056);       // 7,200,000 B
    int*   partial   = (int*)edge_meta;             // alias: dead before scatter

    const int eb3 = (3 * NEDGE + 255) / 256;
    const int gb  = (2 * N_NODE + 3) / 4;           // 4 waves/block

    // 1. all three GEMMs + projections in one launch
    gemm_proj_all<<<3 * 2500, 128, 0, stream>>>(
        feat_drug, feat_disease, W_ind, b_ind, a_ind,
        W_rev, b_rev, a_rev, W_dd, b_dd, a_dd, Wh_all, el_all, er_all);

    // 2-6. one CSR over all 60000 (etype,dst) rows
    fill_i32<<<(NROW + 255) / 256, 256, 0, stream>>>(cnt, 0, NROW);
    hist_all<<<eb3, 256, 0, stream>>>(dst_rev, dst_ind, dst_dd, cnt);
    scan_local<<<NBS, 256, 0, stream>>>(cnt, partial, bsums, NROW);
    scan_tops<<<1, 64, 0, stream>>>(bsums, NBS);
    scan_add<<<NBS, 256, 0, stream>>>(partial, bsums, row_ptr, cnt, s, NROW,
                                      3 * NEDGE);
    scatter_all<<<eb3, 256, 0, stream>>>(src_rev, dst_rev, src_ind, dst_ind,
                                         src_dd, dst_dd, el_all, er_all,
                                         cnt, edge_meta, s);

    // 7. one gather: 40000 output rows, disease rows merge ind+dd in-register
    gather_all<<<gb, 256, 0, stream>>>(row_ptr, edge_meta, s, Wh_all, out);
}

// Round 8
// 283.717 us; speedup vs baseline: 2.1013x; 1.1631x over previous
//
#include <hip/hip_runtime.h>
#include <hip/hip_bf16.h>

typedef __hip_bfloat16 bf16;

#define N_NODE 20000
#define D      128
#define NEDGE  300000
#define NROW   (3 * N_NODE)          // CSR rows: [rev | ind | dd] x dst-node
#define NBS    ((NROW + 255) / 256)  // scan blocks = 235

// ---------------------------------------------------------------- fill
__global__ void fill_i32(int* __restrict__ p, int v, int n) {
    int i = blockIdx.x * blockDim.x + threadIdx.x;
    int stride = gridDim.x * blockDim.x;
    for (; i < n; i += stride) p[i] = v;
}

// ---------------------------------------------------------------- fused GEMM + projections
// grid = 3*2500 blocks; t = etype (0=rev,1=ind,2=dd). 8 nodes/block of 128
// threads; thread j owns col j. Feat rows staged via LDS (round-5 lesson:
// per-lane "uniform" float4 loads are not scalarized -> vmcnt-bound).
// el/er cross-wiring: t=0 Wh_rev -> el[rev], er[ind]; t=1 Wh_ind -> el[ind],
// er[rev]; t=2 Wh_dd -> el[dd], er[dd].
__global__ __launch_bounds__(128) void gemm_proj_all(
    const float* __restrict__ feat_drug, const float* __restrict__ feat_dis,
    const float* __restrict__ W_ind, const float* __restrict__ b_ind,
    const float* __restrict__ a_ind,
    const float* __restrict__ W_rev, const float* __restrict__ b_rev,
    const float* __restrict__ a_rev,
    const float* __restrict__ W_dd, const float* __restrict__ b_dd,
    const float* __restrict__ a_dd,
    bf16* __restrict__ Wh_all, float* __restrict__ el_all,
    float* __restrict__ er_all) {
    __shared__ float fs[8 * D];           // 4 KB
    __shared__ float redA[2][8];
    __shared__ float redB[2][8];
    const int t = blockIdx.x / 2500;
    const int b = blockIdx.x - t * 2500;
    const int j = threadIdx.x;
    const int n0 = b * 8;

    const float *feat, *W, *bias, *va, *vb;
    float *el_o, *er_o;
    if (t == 0)      { feat = feat_dis;  W = W_rev; bias = b_rev; va = a_rev; vb = a_ind + D; el_o = el_all;              er_o = er_all + N_NODE; }
    else if (t == 1) { feat = feat_drug; W = W_ind; bias = b_ind; va = a_ind; vb = a_rev + D; el_o = el_all + N_NODE;     er_o = er_all; }
    else             { feat = feat_dis;  W = W_dd;  bias = b_dd;  va = a_dd;  vb = a_dd + D;  el_o = el_all + 2 * N_NODE; er_o = er_all + 2 * N_NODE; }
    bf16* wh_o = Wh_all + (size_t)t * N_NODE * D;

    {   // cooperative stage: 8 rows x 128 f32 = 256 float4; 2 per thread
        const float4* srcv = (const float4*)(feat + (size_t)n0 * D);
        float4* dstv = (float4*)fs;
        dstv[j] = srcv[j];
        dstv[j + 128] = srcv[j + 128];
    }
    const float vaj = va[j];
    const float vbj = vb[j];
    const float bj  = bias[j];
    __syncthreads();

    float acc[8];
#pragma unroll
    for (int n = 0; n < 8; ++n) acc[n] = bj;

    for (int k = 0; k < D; k += 4) {
        const float w0 = W[(k + 0) * D + j];
        const float w1 = W[(k + 1) * D + j];
        const float w2 = W[(k + 2) * D + j];
        const float w3 = W[(k + 3) * D + j];
        float4 f[8];
#pragma unroll
        for (int n = 0; n < 8; ++n) f[n] = *(const float4*)(fs + n * D + k);
#pragma unroll
        for (int n = 0; n < 8; ++n) {
            acc[n] = fmaf(f[n].x, w0, acc[n]);
            acc[n] = fmaf(f[n].y, w1, acc[n]);
            acc[n] = fmaf(f[n].z, w2, acc[n]);
            acc[n] = fmaf(f[n].w, w3, acc[n]);
        }
    }

    const int wave = j >> 6, lane = j & 63;
#pragma unroll
    for (int n = 0; n < 8; ++n) {
        const float a = acc[n];
        wh_o[(size_t)(n0 + n) * D + j] = __float2bfloat16(a);
        float ea = a * vaj;
        float eb = a * vbj;
#pragma unroll
        for (int off = 32; off > 0; off >>= 1) {
            ea += __shfl_down(ea, off, 64);
            eb += __shfl_down(eb, off, 64);
        }
        if (lane == 0) { redA[wave][n] = ea; redB[wave][n] = eb; }
    }
    __syncthreads();
    if (j < 8)       el_o[n0 + j]     = redA[0][j] + redA[1][j];
    else if (j < 16) er_o[n0 + j - 8] = redB[0][j - 8] + redB[1][j - 8];
}

// ---------------------------------------------------------------- CSR build
__global__ __launch_bounds__(256) void hist_all(
    const int* __restrict__ dst_rev, const int* __restrict__ dst_ind,
    const int* __restrict__ dst_dd, int* __restrict__ cnt) {
    int i = blockIdx.x * blockDim.x + threadIdx.x;
    int stride = gridDim.x * blockDim.x;
    for (; i < 3 * NEDGE; i += stride) {
        const int t = (i >= 2 * NEDGE) ? 2 : (i >= NEDGE ? 1 : 0);
        const int e = i - t * NEDGE;
        const int d = (t == 0 ? dst_rev : (t == 1 ? dst_ind : dst_dd))[e];
        atomicAdd(&cnt[t * N_NODE + d], 1);
    }
}

// hierarchical scan, stage 1: per-block (256) exclusive scan + block total
__global__ __launch_bounds__(256) void scan_local(
    const int* __restrict__ cnt, int* __restrict__ partial,
    int* __restrict__ block_sums, int n) {
    __shared__ int wsum[4];
    const int idx = blockIdx.x * 256 + threadIdx.x;
    const int lane = threadIdx.x & 63, wave = threadIdx.x >> 6;
    int v = (idx < n) ? cnt[idx] : 0;
    const int orig = v;
#pragma unroll
    for (int off = 1; off < 64; off <<= 1) {
        int t = __shfl_up(v, off, 64);
        if (lane >= off) v += t;
    }
    if (lane == 63) wsum[wave] = v;
    __syncthreads();
    if (threadIdx.x == 0) {
        int a = 0;
#pragma unroll
        for (int w = 0; w < 4; ++w) { int t = wsum[w]; wsum[w] = a; a += t; }
    }
    __syncthreads();
    const int incl = wsum[wave] + v;
    if (idx < n) partial[idx] = incl - orig;   // exclusive within block
    if (threadIdx.x == 255) block_sums[blockIdx.x] = incl;
}

// stage 2: single wave scans the block totals (exclusive, in place)
__global__ __launch_bounds__(64) void scan_tops(int* __restrict__ bs, int nb) {
    const int lane = threadIdx.x;
    int carry = 0;
    for (int base = 0; base < nb; base += 64) {
        int v = (base + lane < nb) ? bs[base + lane] : 0;
        const int orig = v;
#pragma unroll
        for (int off = 1; off < 64; off <<= 1) {
            int t = __shfl_up(v, off, 64);
            if (lane >= off) v += t;
        }
        if (base + lane < nb) bs[base + lane] = carry + v - orig;
        carry += __shfl(v, 63, 64);
    }
}

// stage 3: add block offsets; write row_ptr + cursor
__global__ __launch_bounds__(256) void scan_add(
    const int* __restrict__ partial, const int* __restrict__ block_sums,
    int* __restrict__ row_ptr, int* __restrict__ cursor, int n, int total) {
    const int idx = blockIdx.x * 256 + threadIdx.x;
    if (idx < n) {
        const int r = partial[idx] + block_sums[blockIdx.x];
        row_ptr[idx] = r;
        cursor[idx] = r;
    }
    if (idx == 0) row_ptr[n] = total;
}

// fused scatter over all 3 edge lists. Round-7 lesson: 8B random stores +
// s/pe atomics caused 83MB of line-granular writeback (11x amplification,
// 95us). Now the scattered payload is a single USHORT (global src row
// < 60000): 1.8MB total, L2-resident. pe and the segment sum are NOT stored
// — gather recomputes them from el/er (240KB, L2-hot).
__global__ __launch_bounds__(256) void scatter_all(
    const int* __restrict__ src_rev, const int* __restrict__ dst_rev,
    const int* __restrict__ src_ind, const int* __restrict__ dst_ind,
    const int* __restrict__ src_dd,  const int* __restrict__ dst_dd,
    int* __restrict__ cursor, unsigned short* __restrict__ edge_src16) {
    int i = blockIdx.x * blockDim.x + threadIdx.x;
    int stride = gridDim.x * blockDim.x;
    for (; i < 3 * NEDGE; i += stride) {
        const int t = (i >= 2 * NEDGE) ? 2 : (i >= NEDGE ? 1 : 0);
        const int e = i - t * NEDGE;
        const int sl = (t == 0 ? src_rev : (t == 1 ? src_ind : src_dd))[e];
        const int dl = (t == 0 ? dst_rev : (t == 1 ? dst_ind : dst_dd))[e];
        const int slot = atomicAdd(&cursor[t * N_NODE + dl], 1);
        edge_src16[slot] = (unsigned short)(t * N_NODE + sl);
    }
}

// ---------------------------------------------------------------- gather
// One CSR range: pass 1 recomputes pe per lane-owned edge (coalesced ushort
// load + L2-hot el gather + exp) and wave-reduces the softmax denominator
// (deterministic — closer to ref than the old atomic-ordered sum); pass 2
// broadcasts (src, pe) via shfl and gathers Wh rows with x4 unroll.
__device__ __forceinline__ void do_range(
    const unsigned short* __restrict__ edge_src16,
    const float* __restrict__ el_all, float er_r,
    const bf16* __restrict__ Wh_all,
    int beg, int end, int lane, float& a0, float& a1) {
    if (end <= beg) return;

    float ssum = 0.f;
    for (int base = beg; base < end; base += 64) {
        const int m = min(end - base, 64);
        if (lane < m) {
            const int sr = edge_src16[base + lane];
            float v = el_all[sr] + er_r;
            v = v > 0.f ? v : 0.01f * v;
            ssum += __expf(v);
        }
    }
#pragma unroll
    for (int off = 32; off > 0; off >>= 1) ssum += __shfl_down(ssum, off, 64);
    const float inv = 1.0f / __shfl(ssum, 0, 64);

    for (int base = beg; base < end; base += 64) {
        const int m = min(end - base, 64);
        int msrc = 0; float mpe = 0.f;
        if (lane < m) {
            msrc = edge_src16[base + lane];
            float v = el_all[msrc] + er_r;
            v = v > 0.f ? v : 0.01f * v;
            mpe = __expf(v);
        }
        int t = 0;
        for (; t + 4 <= m; t += 4) {
            const int s0 = __shfl(msrc, t,     64);
            const int s1 = __shfl(msrc, t + 1, 64);
            const int s2 = __shfl(msrc, t + 2, 64);
            const int s3 = __shfl(msrc, t + 3, 64);
            const float c0 = __shfl(mpe, t,     64) * inv;
            const float c1 = __shfl(mpe, t + 1, 64) * inv;
            const float c2 = __shfl(mpe, t + 2, 64) * inv;
            const float c3 = __shfl(mpe, t + 3, 64) * inv;
            const unsigned u0 = ((const unsigned*)(Wh_all + (size_t)s0 * D))[lane];
            const unsigned u1 = ((const unsigned*)(Wh_all + (size_t)s1 * D))[lane];
            const unsigned u2 = ((const unsigned*)(Wh_all + (size_t)s2 * D))[lane];
            const unsigned u3 = ((const unsigned*)(Wh_all + (size_t)s3 * D))[lane];
            a0 = fmaf(c0, __uint_as_float(u0 << 16), a0);
            a1 = fmaf(c0, __uint_as_float(u0 & 0xFFFF0000u), a1);
            a0 = fmaf(c1, __uint_as_float(u1 << 16), a0);
            a1 = fmaf(c1, __uint_as_float(u1 & 0xFFFF0000u), a1);
            a0 = fmaf(c2, __uint_as_float(u2 << 16), a0);
            a1 = fmaf(c2, __uint_as_float(u2 & 0xFFFF0000u), a1);
            a0 = fmaf(c3, __uint_as_float(u3 << 16), a0);
            a1 = fmaf(c3, __uint_as_float(u3 & 0xFFFF0000u), a1);
        }
        for (; t < m; ++t) {
            const int s0 = __shfl(msrc, t, 64);
            const float c0 = __shfl(mpe, t, 64) * inv;
            const unsigned u0 = ((const unsigned*)(Wh_all + (size_t)s0 * D))[lane];
            a0 = fmaf(c0, __uint_as_float(u0 << 16), a0);
            a1 = fmaf(c0, __uint_as_float(u0 & 0xFFFF0000u), a1);
        }
    }
}

// One wave per OUTPUT row w in [0,40000): w<20000 -> h_drug (CSR row w, rev);
// w>=20000 -> h_disease (CSR rows w [ind] and w+20000 [dd], each with its own
// softmax normalizer). Single f32x2 store per lane.
__global__ __launch_bounds__(256) void gather_all(
    const int* __restrict__ row_ptr, const unsigned short* __restrict__ edge_src16,
    const float* __restrict__ el_all, const float* __restrict__ er_all,
    const bf16* __restrict__ Wh_all, float* __restrict__ out) {
    const int w = blockIdx.x * (blockDim.x >> 6) + (threadIdx.x >> 6);
    const int lane = threadIdx.x & 63;
    if (w >= 2 * N_NODE) return;

    float a0 = 0.f, a1 = 0.f;
    do_range(edge_src16, el_all, er_all[w], Wh_all,
             row_ptr[w], row_ptr[w + 1], lane, a0, a1);
    if (w >= N_NODE) {   // disease row: add the disease_disease contribution
        const int r = w + N_NODE;
        do_range(edge_src16, el_all, er_all[r], Wh_all,
                 row_ptr[r], row_ptr[r + 1], lane, a0, a1);
    }
    ((float2*)(out + (size_t)w * D))[lane] = make_float2(a0, a1);
}

extern "C" void kernel_launch(void* const* d_in, const int* in_sizes, int n_in,
                              void* d_out, int out_size, void* d_ws, size_t ws_size,
                              hipStream_t stream) {
    const float* feat_drug    = (const float*)d_in[0];
    const float* feat_disease = (const float*)d_in[1];
    const float* W_ind = (const float*)d_in[2];
    const float* b_ind = (const float*)d_in[3];
    const float* a_ind = (const float*)d_in[4];
    const float* W_rev = (const float*)d_in[5];
    const float* b_rev = (const float*)d_in[6];
    const float* a_rev = (const float*)d_in[7];
    const float* W_dd  = (const float*)d_in[8];
    const float* b_dd  = (const float*)d_in[9];
    const float* a_dd  = (const float*)d_in[10];
    const int* src_ind = (const int*)d_in[11];
    const int* dst_ind = (const int*)d_in[12];
    const int* src_rev = (const int*)d_in[13];
    const int* dst_rev = (const int*)d_in[14];
    const int* src_dd  = (const int*)d_in[15];
    const int* dst_dd  = (const int*)d_in[16];
    float* out = (float*)d_out;
    (void)in_sizes; (void)n_in; (void)out_size; (void)ws_size;

    // ---- workspace: ~18.4 MB ----
    char* w = (char*)d_ws;
    bf16*  Wh_all    = (bf16*)w;                       // 15,360,000 B [rev|ind|dd]
    float* el_all    = (float*)(w + 15360000);         // 240,000 B
    float* er_all    = (float*)(w + 15600000);         // 240,000 B
    int*   row_ptr   = (int*)(w + 15840000);           // 240,004 -> pad 240,032
    int*   cnt       = (int*)(w + 16080032);           // 240,000 B (cursor)
    int*   bsums     = (int*)(w + 16320032);           // 1,024 B
    int*   partial   = (int*)(w + 16321056);           // 240,000 B
    unsigned short* edge_src16 = (unsigned short*)(w + 16561056); // 1,800,000 B

    const int eb3 = (3 * NEDGE + 255) / 256;
    const int gb  = (2 * N_NODE + 3) / 4;              // 4 waves/block

    // 1. all three GEMMs + projections in one launch
    gemm_proj_all<<<3 * 2500, 128, 0, stream>>>(
        feat_drug, feat_disease, W_ind, b_ind, a_ind,
        W_rev, b_rev, a_rev, W_dd, b_dd, a_dd, Wh_all, el_all, er_all);

    // 2-6. one CSR over all 60000 (etype,dst) rows
    fill_i32<<<(NROW + 255) / 256, 256, 0, stream>>>(cnt, 0, NROW);
    hist_all<<<eb3, 256, 0, stream>>>(dst_rev, dst_ind, dst_dd, cnt);
    scan_local<<<NBS, 256, 0, stream>>>(cnt, partial, bsums, NROW);
    scan_tops<<<1, 64, 0, stream>>>(bsums, NBS);
    scan_add<<<NBS, 256, 0, stream>>>(partial, bsums, row_ptr, cnt, NROW,
                                      3 * NEDGE);
    scatter_all<<<eb3, 256, 0, stream>>>(src_rev, dst_rev, src_ind, dst_ind,
                                         src_dd, dst_dd, cnt, edge_src16);

    // 7. one gather: 40000 output rows, disease rows merge ind+dd in-register
    gather_all<<<gb, 256, 0, stream>>>(row_ptr, edge_src16, el_all, er_all,
                                       Wh_all, out);
}

// Round 9
// 251.262 us; speedup vs baseline: 2.3727x; 1.1292x over previous
//
#include <hip/hip_runtime.h>
#include <hip/hip_bf16.h>

typedef __hip_bfloat16 bf16;
typedef __attribute__((ext_vector_type(8))) short bf16x8;
typedef __attribute__((ext_vector_type(4))) float f32x4;

#define N_NODE 20000
#define D      128
#define NEDGE  300000
#define NROW   (3 * N_NODE)          // CSR rows: [rev | ind | dd] x dst-node
#define NBS    ((NROW + 255) / 256)  // scan blocks = 235
#define GBE    ((N_NODE + 63) / 64)  // gemm blocks per etype = 313
#define WT_LD  132                   // padded LDS leading dim (bank-conflict-free)

__device__ __forceinline__ short f2bs(float x) {
    bf16 h = __float2bfloat16(x);
    short s; __builtin_memcpy(&s, &h, 2); return s;
}

// ---------------------------------------------------------------- fill
__global__ void fill_i32(int* __restrict__ p, int v, int n) {
    int i = blockIdx.x * blockDim.x + threadIdx.x;
    int stride = gridDim.x * blockDim.x;
    for (; i < n; i += stride) p[i] = v;
}

// ---------------------------------------------------------------- MFMA GEMM + projections
// Round-8 lesson: the VALU GEMM was LDS-read-throughput-bound (8 ds_read_b128
// per 4-k step ~= 75us of LDS pipe). MFMA version: block = 4 waves x 16 rows;
// W staged transposed+padded in LDS as bf16; per wave 32 x mfma_16x16x32_bf16.
// Verified layouts (m89/m120): A[m=lane&15][k=quad*8+j]; B[k=quad*8+j][n=lane&15];
// D: row=quad*4+reg, col=lane&15.
// el/er cross-wiring: t=0 Wh_rev -> el[rev], er[ind]; t=1 Wh_ind -> el[ind],
// er[rev]; t=2 Wh_dd -> el[dd], er[dd].
__global__ __launch_bounds__(256) void gemm_mfma_all(
    const float* __restrict__ feat_drug, const float* __restrict__ feat_dis,
    const float* __restrict__ W_ind, const float* __restrict__ b_ind,
    const float* __restrict__ a_ind,
    const float* __restrict__ W_rev, const float* __restrict__ b_rev,
    const float* __restrict__ a_rev,
    const float* __restrict__ W_dd, const float* __restrict__ b_dd,
    const float* __restrict__ a_dd,
    bf16* __restrict__ Wh_all, float* __restrict__ el_all,
    float* __restrict__ er_all) {
    __shared__ short Wt[D * WT_LD];       // W transposed [n][k], bf16, 33.8 KB
    const int t  = blockIdx.x / GBE;
    const int mb = blockIdx.x - t * GBE;
    const int tid = threadIdx.x;

    const float *feat, *W, *bias, *va, *vb;
    float *el_o, *er_o;
    if (t == 0)      { feat = feat_dis;  W = W_rev; bias = b_rev; va = a_rev; vb = a_ind + D; el_o = el_all;              er_o = er_all + N_NODE; }
    else if (t == 1) { feat = feat_drug; W = W_ind; bias = b_ind; va = a_ind; vb = a_rev + D; el_o = el_all + N_NODE;     er_o = er_all; }
    else             { feat = feat_dis;  W = W_dd;  bias = b_dd;  va = a_dd;  vb = a_dd + D;  el_o = el_all + 2 * N_NODE; er_o = er_all + 2 * N_NODE; }
    bf16* wh_o = Wh_all + (size_t)t * N_NODE * D;

    // stage W -> LDS transposed bf16 (64 KB L2-hot read, 16 float4/thread)
    for (int i = tid * 4; i < D * D; i += 1024) {
        const float4 wv = *(const float4*)(W + i);
        const int k = i >> 7, n = i & (D - 1);
        Wt[(n + 0) * WT_LD + k] = f2bs(wv.x);
        Wt[(n + 1) * WT_LD + k] = f2bs(wv.y);
        Wt[(n + 2) * WT_LD + k] = f2bs(wv.z);
        Wt[(n + 3) * WT_LD + k] = f2bs(wv.w);
    }
    __syncthreads();

    const int wave = tid >> 6, lane = tid & 63;
    const int q = lane >> 4, nn = lane & 15;
    const int row0 = mb * 64 + wave * 16;            // wave's first M row
    const int arow = min(row0 + nn, N_NODE - 1);     // A row this lane feeds

    f32x4 acc[8];
#pragma unroll
    for (int nt = 0; nt < 8; ++nt) acc[nt] = (f32x4){0.f, 0.f, 0.f, 0.f};

#pragma unroll
    for (int ks = 0; ks < 4; ++ks) {
        const float* ap = feat + (size_t)arow * D + ks * 32 + q * 8;
        const float4 fa = *(const float4*)ap;
        const float4 fb = *(const float4*)(ap + 4);
        bf16x8 afrag;
        afrag[0] = f2bs(fa.x); afrag[1] = f2bs(fa.y);
        afrag[2] = f2bs(fa.z); afrag[3] = f2bs(fa.w);
        afrag[4] = f2bs(fb.x); afrag[5] = f2bs(fb.y);
        afrag[6] = f2bs(fb.z); afrag[7] = f2bs(fb.w);
#pragma unroll
        for (int nt = 0; nt < 8; ++nt) {
            const bf16x8 bfrag =
                *(const bf16x8*)(&Wt[(nt * 16 + nn) * WT_LD + ks * 32 + q * 8]);
            acc[nt] = __builtin_amdgcn_mfma_f32_16x16x32_bf16(afrag, bfrag,
                                                              acc[nt], 0, 0, 0);
        }
    }

    // epilogue: bias, Wh store (bf16), el/er row reductions
    float biasv[8], vav[8], vbv[8];
#pragma unroll
    for (int nt = 0; nt < 8; ++nt) {
        const int col = nt * 16 + nn;
        biasv[nt] = bias[col]; vav[nt] = va[col]; vbv[nt] = vb[col];
    }
    float pel[4] = {0.f, 0.f, 0.f, 0.f};
    float per_[4] = {0.f, 0.f, 0.f, 0.f};
    short* whs = (short*)wh_o;
#pragma unroll
    for (int nt = 0; nt < 8; ++nt) {
#pragma unroll
        for (int r = 0; r < 4; ++r) {
            const float c = acc[nt][r] + biasv[nt];
            const int grow = row0 + q * 4 + r;
            if (grow < N_NODE)
                whs[(size_t)grow * D + nt * 16 + nn] = f2bs(c);
            pel[r] = fmaf(c, vav[nt], pel[r]);
            per_[r] = fmaf(c, vbv[nt], per_[r]);
        }
    }
#pragma unroll
    for (int r = 0; r < 4; ++r) {
#pragma unroll
        for (int mask = 1; mask < 16; mask <<= 1) {
            pel[r]  += __shfl_xor(pel[r],  mask, 64);
            per_[r] += __shfl_xor(per_[r], mask, 64);
        }
        const int grow = row0 + q * 4 + r;
        if (nn == 0 && grow < N_NODE) {
            el_o[grow] = pel[r];
            er_o[grow] = per_[r];
        }
    }
}

// ---------------------------------------------------------------- CSR build
__global__ __launch_bounds__(256) void hist_all(
    const int* __restrict__ dst_rev, const int* __restrict__ dst_ind,
    const int* __restrict__ dst_dd, int* __restrict__ cnt) {
    int i = blockIdx.x * blockDim.x + threadIdx.x;
    int stride = gridDim.x * blockDim.x;
    for (; i < 3 * NEDGE; i += stride) {
        const int t = (i >= 2 * NEDGE) ? 2 : (i >= NEDGE ? 1 : 0);
        const int e = i - t * NEDGE;
        const int d = (t == 0 ? dst_rev : (t == 1 ? dst_ind : dst_dd))[e];
        atomicAdd(&cnt[t * N_NODE + d], 1);
    }
}

// hierarchical scan, stage 1: per-block (256) exclusive scan + block total
__global__ __launch_bounds__(256) void scan_local(
    const int* __restrict__ cnt, int* __restrict__ partial,
    int* __restrict__ block_sums, int n) {
    __shared__ int wsum[4];
    const int idx = blockIdx.x * 256 + threadIdx.x;
    const int lane = threadIdx.x & 63, wave = threadIdx.x >> 6;
    int v = (idx < n) ? cnt[idx] : 0;
    const int orig = v;
#pragma unroll
    for (int off = 1; off < 64; off <<= 1) {
        int t = __shfl_up(v, off, 64);
        if (lane >= off) v += t;
    }
    if (lane == 63) wsum[wave] = v;
    __syncthreads();
    if (threadIdx.x == 0) {
        int a = 0;
#pragma unroll
        for (int w = 0; w < 4; ++w) { int t = wsum[w]; wsum[w] = a; a += t; }
    }
    __syncthreads();
    const int incl = wsum[wave] + v;
    if (idx < n) partial[idx] = incl - orig;   // exclusive within block
    if (threadIdx.x == 255) block_sums[blockIdx.x] = incl;
}

// stage 2: single wave scans the block totals (exclusive, in place)
__global__ __launch_bounds__(64) void scan_tops(int* __restrict__ bs, int nb) {
    const int lane = threadIdx.x;
    int carry = 0;
    for (int base = 0; base < nb; base += 64) {
        int v = (base + lane < nb) ? bs[base + lane] : 0;
        const int orig = v;
#pragma unroll
        for (int off = 1; off < 64; off <<= 1) {
            int t = __shfl_up(v, off, 64);
            if (lane >= off) v += t;
        }
        if (base + lane < nb) bs[base + lane] = carry + v - orig;
        carry += __shfl(v, 63, 64);
    }
}

// stage 3: add block offsets; write row_ptr + cursor
__global__ __launch_bounds__(256) void scan_add(
    const int* __restrict__ partial, const int* __restrict__ block_sums,
    int* __restrict__ row_ptr, int* __restrict__ cursor, int n, int total) {
    const int idx = blockIdx.x * 256 + threadIdx.x;
    if (idx < n) {
        const int r = partial[idx] + block_sums[blockIdx.x];
        row_ptr[idx] = r;
        cursor[idx] = r;
    }
    if (idx == 0) row_ptr[n] = total;
}

// fused scatter over all 3 edge lists. Round-7 lesson: 8B random stores +
// s/pe atomics caused 83MB of line-granular writeback (11x amplification).
// Payload is a single USHORT (global src row < 60000): 1.8MB, L2-resident.
__global__ __launch_bounds__(256) void scatter_all(
    const int* __restrict__ src_rev, const int* __restrict__ dst_rev,
    const int* __restrict__ src_ind, const int* __restrict__ dst_ind,
    const int* __restrict__ src_dd,  const int* __restrict__ dst_dd,
    int* __restrict__ cursor, unsigned short* __restrict__ edge_src16) {
    int i = blockIdx.x * blockDim.x + threadIdx.x;
    int stride = gridDim.x * blockDim.x;
    for (; i < 3 * NEDGE; i += stride) {
        const int t = (i >= 2 * NEDGE) ? 2 : (i >= NEDGE ? 1 : 0);
        const int e = i - t * NEDGE;
        const int sl = (t == 0 ? src_rev : (t == 1 ? src_ind : src_dd))[e];
        const int dl = (t == 0 ? dst_rev : (t == 1 ? dst_ind : dst_dd))[e];
        const int slot = atomicAdd(&cursor[t * N_NODE + dl], 1);
        edge_src16[slot] = (unsigned short)(t * N_NODE + sl);
    }
}

// ---------------------------------------------------------------- gather
// pass 1 recomputes pe per lane-owned edge and wave-reduces the softmax
// denominator (deterministic); pass 2 broadcasts (src, pe) via shfl and
// gathers Wh rows with x4 unroll.
__device__ __forceinline__ void do_range(
    const unsigned short* __restrict__ edge_src16,
    const float* __restrict__ el_all, float er_r,
    const bf16* __restrict__ Wh_all,
    int beg, int end, int lane, float& a0, float& a1) {
    if (end <= beg) return;

    float ssum = 0.f;
    for (int base = beg; base < end; base += 64) {
        const int m = min(end - base, 64);
        if (lane < m) {
            const int sr = edge_src16[base + lane];
            float v = el_all[sr] + er_r;
            v = v > 0.f ? v : 0.01f * v;
            ssum += __expf(v);
        }
    }
#pragma unroll
    for (int off = 32; off > 0; off >>= 1) ssum += __shfl_down(ssum, off, 64);
    const float inv = 1.0f / __shfl(ssum, 0, 64);

    for (int base = beg; base < end; base += 64) {
        const int m = min(end - base, 64);
        int msrc = 0; float mpe = 0.f;
        if (lane < m) {
            msrc = edge_src16[base + lane];
            float v = el_all[msrc] + er_r;
            v = v > 0.f ? v : 0.01f * v;
            mpe = __expf(v);
        }
        int t = 0;
        for (; t + 4 <= m; t += 4) {
            const int s0 = __shfl(msrc, t,     64);
            const int s1 = __shfl(msrc, t + 1, 64);
            const int s2 = __shfl(msrc, t + 2, 64);
            const int s3 = __shfl(msrc, t + 3, 64);
            const float c0 = __shfl(mpe, t,     64) * inv;
            const float c1 = __shfl(mpe, t + 1, 64) * inv;
            const float c2 = __shfl(mpe, t + 2, 64) * inv;
            const float c3 = __shfl(mpe, t + 3, 64) * inv;
            const unsigned u0 = ((const unsigned*)(Wh_all + (size_t)s0 * D))[lane];
            const unsigned u1 = ((const unsigned*)(Wh_all + (size_t)s1 * D))[lane];
            const unsigned u2 = ((const unsigned*)(Wh_all + (size_t)s2 * D))[lane];
            const unsigned u3 = ((const unsigned*)(Wh_all + (size_t)s3 * D))[lane];
            a0 = fmaf(c0, __uint_as_float(u0 << 16), a0);
            a1 = fmaf(c0, __uint_as_float(u0 & 0xFFFF0000u), a1);
            a0 = fmaf(c1, __uint_as_float(u1 << 16), a0);
            a1 = fmaf(c1, __uint_as_float(u1 & 0xFFFF0000u), a1);
            a0 = fmaf(c2, __uint_as_float(u2 << 16), a0);
            a1 = fmaf(c2, __uint_as_float(u2 & 0xFFFF0000u), a1);
            a0 = fmaf(c3, __uint_as_float(u3 << 16), a0);
            a1 = fmaf(c3, __uint_as_float(u3 & 0xFFFF0000u), a1);
        }
        for (; t < m; ++t) {
            const int s0 = __shfl(msrc, t, 64);
            const float c0 = __shfl(mpe, t, 64) * inv;
            const unsigned u0 = ((const unsigned*)(Wh_all + (size_t)s0 * D))[lane];
            a0 = fmaf(c0, __uint_as_float(u0 << 16), a0);
            a1 = fmaf(c0, __uint_as_float(u0 & 0xFFFF0000u), a1);
        }
    }
}

// One wave per OUTPUT row w in [0,40000): w<20000 -> h_drug (CSR row w, rev);
// w>=20000 -> h_disease (CSR rows w [ind] and w+20000 [dd]).
__global__ __launch_bounds__(256) void gather_all(
    const int* __restrict__ row_ptr, const unsigned short* __restrict__ edge_src16,
    const float* __restrict__ el_all, const float* __restrict__ er_all,
    const bf16* __restrict__ Wh_all, float* __restrict__ out) {
    const int w = blockIdx.x * (blockDim.x >> 6) + (threadIdx.x >> 6);
    const int lane = threadIdx.x & 63;
    if (w >= 2 * N_NODE) return;

    float a0 = 0.f, a1 = 0.f;
    do_range(edge_src16, el_all, er_all[w], Wh_all,
             row_ptr[w], row_ptr[w + 1], lane, a0, a1);
    if (w >= N_NODE) {   // disease row: add the disease_disease contribution
        const int r = w + N_NODE;
        do_range(edge_src16, el_all, er_all[r], Wh_all,
                 row_ptr[r], row_ptr[r + 1], lane, a0, a1);
    }
    ((float2*)(out + (size_t)w * D))[lane] = make_float2(a0, a1);
}

extern "C" void kernel_launch(void* const* d_in, const int* in_sizes, int n_in,
                              void* d_out, int out_size, void* d_ws, size_t ws_size,
                              hipStream_t stream) {
    const float* feat_drug    = (const float*)d_in[0];
    const float* feat_disease = (const float*)d_in[1];
    const float* W_ind = (const float*)d_in[2];
    const float* b_ind = (const float*)d_in[3];
    const float* a_ind = (const float*)d_in[4];
    const float* W_rev = (const float*)d_in[5];
    const float* b_rev = (const float*)d_in[6];
    const float* a_rev = (const float*)d_in[7];
    const float* W_dd  = (const float*)d_in[8];
    const float* b_dd  = (const float*)d_in[9];
    const float* a_dd  = (const float*)d_in[10];
    const int* src_ind = (const int*)d_in[11];
    const int* dst_ind = (const int*)d_in[12];
    const int* src_rev = (const int*)d_in[13];
    const int* dst_rev = (const int*)d_in[14];
    const int* src_dd  = (const int*)d_in[15];
    const int* dst_dd  = (const int*)d_in[16];
    float* out = (float*)d_out;
    (void)in_sizes; (void)n_in; (void)out_size; (void)ws_size;

    // ---- workspace: ~18.4 MB ----
    char* w = (char*)d_ws;
    bf16*  Wh_all    = (bf16*)w;                       // 15,360,000 B [rev|ind|dd]
    float* el_all    = (float*)(w + 15360000);         // 240,000 B
    float* er_all    = (float*)(w + 15600000);         // 240,000 B
    int*   row_ptr   = (int*)(w + 15840000);           // 240,004 -> pad 240,032
    int*   cnt       = (int*)(w + 16080032);           // 240,000 B (cursor)
    int*   bsums     = (int*)(w + 16320032);           // 1,024 B
    int*   partial   = (int*)(w + 16321056);           // 240,000 B
    unsigned short* edge_src16 = (unsigned short*)(w + 16561056); // 1,800,000 B

    const int eb3 = (3 * NEDGE + 255) / 256;
    const int gb  = (2 * N_NODE + 3) / 4;              // 4 waves/block

    // 1. all three GEMMs + projections in one MFMA launch
    gemm_mfma_all<<<3 * GBE, 256, 0, stream>>>(
        feat_drug, feat_disease, W_ind, b_ind, a_ind,
        W_rev, b_rev, a_rev, W_dd, b_dd, a_dd, Wh_all, el_all, er_all);

    // 2-6. one CSR over all 60000 (etype,dst) rows
    fill_i32<<<(NROW + 255) / 256, 256, 0, stream>>>(cnt, 0, NROW);
    hist_all<<<eb3, 256, 0, stream>>>(dst_rev, dst_ind, dst_dd, cnt);
    scan_local<<<NBS, 256, 0, stream>>>(cnt, partial, bsums, NROW);
    scan_tops<<<1, 64, 0, stream>>>(bsums, NBS);
    scan_add<<<NBS, 256, 0, stream>>>(partial, bsums, row_ptr, cnt, NROW,
                                      3 * NEDGE);
    scatter_all<<<eb3, 256, 0, stream>>>(src_rev, dst_rev, src_ind, dst_ind,
                                         src_dd, dst_dd, cnt, edge_src16);

    // 7. one gather: 40000 output rows, disease rows merge ind+dd in-register
    gather_all<<<gb, 256, 0, stream>>>(row_ptr, edge_src16, el_all, er_all,
                                       Wh_all, out);
}

// Round 10
// 194.865 us; speedup vs baseline: 3.0595x; 1.2894x over previous
//
#include <hip/hip_runtime.h>
#include <hip/hip_bf16.h>

typedef __hip_bfloat16 bf16;
typedef __attribute__((ext_vector_type(8))) short bf16x8;
typedef __attribute__((ext_vector_type(4))) float f32x4;

#define N_NODE 20000
#define D      128
#define NEDGE  300000
#define NROW   (3 * N_NODE)          // CSR rows: [rev | ind | dd] x dst-node
#define NBIN   ((NROW + 255) >> 8)   // 235 bins of 256 rows
#define NB3    220                   // binct/binscat blocks (220*4096 >= 900000)
#define CHUNK  4096
#define GBE    ((N_NODE + 63) / 64)  // gemm blocks per etype = 313
#define WT_LD  132                   // padded LDS leading dim (bank-conflict-free)

__device__ __forceinline__ short f2bs(float x) {
    bf16 h = __float2bfloat16(x);
    short s; __builtin_memcpy(&s, &h, 2); return s;
}

// ---------------------------------------------------------------- MFMA GEMM + projections
// Block = 4 waves x 16 rows; W staged transposed+padded in LDS as bf16; per
// wave 32 x mfma_16x16x32_bf16 (round-8: VALU GEMM was LDS-throughput-bound).
// Layouts (m89/m120): A[m=lane&15][k=quad*8+j]; B[k=quad*8+j][n=lane&15];
// D: row=quad*4+reg, col=lane&15. el/er cross-wiring: t=0 Wh_rev -> el[rev],
// er[ind]; t=1 Wh_ind -> el[ind], er[rev]; t=2 Wh_dd -> el[dd], er[dd].
__global__ __launch_bounds__(256) void gemm_mfma_all(
    const float* __restrict__ feat_drug, const float* __restrict__ feat_dis,
    const float* __restrict__ W_ind, const float* __restrict__ b_ind,
    const float* __restrict__ a_ind,
    const float* __restrict__ W_rev, const float* __restrict__ b_rev,
    const float* __restrict__ a_rev,
    const float* __restrict__ W_dd, const float* __restrict__ b_dd,
    const float* __restrict__ a_dd,
    bf16* __restrict__ Wh_all, float* __restrict__ el_all,
    float* __restrict__ er_all) {
    __shared__ short Wt[D * WT_LD];       // W transposed [n][k], bf16, 33.8 KB
    const int t  = blockIdx.x / GBE;
    const int mb = blockIdx.x - t * GBE;
    const int tid = threadIdx.x;

    const float *feat, *W, *bias, *va, *vb;
    float *el_o, *er_o;
    if (t == 0)      { feat = feat_dis;  W = W_rev; bias = b_rev; va = a_rev; vb = a_ind + D; el_o = el_all;              er_o = er_all + N_NODE; }
    else if (t == 1) { feat = feat_drug; W = W_ind; bias = b_ind; va = a_ind; vb = a_rev + D; el_o = el_all + N_NODE;     er_o = er_all; }
    else             { feat = feat_dis;  W = W_dd;  bias = b_dd;  va = a_dd;  vb = a_dd + D;  el_o = el_all + 2 * N_NODE; er_o = er_all + 2 * N_NODE; }
    bf16* wh_o = Wh_all + (size_t)t * N_NODE * D;

    for (int i = tid * 4; i < D * D; i += 1024) {
        const float4 wv = *(const float4*)(W + i);
        const int k = i >> 7, n = i & (D - 1);
        Wt[(n + 0) * WT_LD + k] = f2bs(wv.x);
        Wt[(n + 1) * WT_LD + k] = f2bs(wv.y);
        Wt[(n + 2) * WT_LD + k] = f2bs(wv.z);
        Wt[(n + 3) * WT_LD + k] = f2bs(wv.w);
    }
    __syncthreads();

    const int wave = tid >> 6, lane = tid & 63;
    const int q = lane >> 4, nn = lane & 15;
    const int row0 = mb * 64 + wave * 16;
    const int arow = min(row0 + nn, N_NODE - 1);

    f32x4 acc[8];
#pragma unroll
    for (int nt = 0; nt < 8; ++nt) acc[nt] = (f32x4){0.f, 0.f, 0.f, 0.f};

#pragma unroll
    for (int ks = 0; ks < 4; ++ks) {
        const float* ap = feat + (size_t)arow * D + ks * 32 + q * 8;
        const float4 fa = *(const float4*)ap;
        const float4 fb = *(const float4*)(ap + 4);
        bf16x8 afrag;
        afrag[0] = f2bs(fa.x); afrag[1] = f2bs(fa.y);
        afrag[2] = f2bs(fa.z); afrag[3] = f2bs(fa.w);
        afrag[4] = f2bs(fb.x); afrag[5] = f2bs(fb.y);
        afrag[6] = f2bs(fb.z); afrag[7] = f2bs(fb.w);
#pragma unroll
        for (int nt = 0; nt < 8; ++nt) {
            const bf16x8 bfrag =
                *(const bf16x8*)(&Wt[(nt * 16 + nn) * WT_LD + ks * 32 + q * 8]);
            acc[nt] = __builtin_amdgcn_mfma_f32_16x16x32_bf16(afrag, bfrag,
                                                              acc[nt], 0, 0, 0);
        }
    }

    float biasv[8], vav[8], vbv[8];
#pragma unroll
    for (int nt = 0; nt < 8; ++nt) {
        const int col = nt * 16 + nn;
        biasv[nt] = bias[col]; vav[nt] = va[col]; vbv[nt] = vb[col];
    }
    float pel[4] = {0.f, 0.f, 0.f, 0.f};
    float per_[4] = {0.f, 0.f, 0.f, 0.f};
    short* whs = (short*)wh_o;
#pragma unroll
    for (int nt = 0; nt < 8; ++nt) {
#pragma unroll
        for (int r = 0; r < 4; ++r) {
            const float c = acc[nt][r] + biasv[nt];
            const int grow = row0 + q * 4 + r;
            if (grow < N_NODE)
                whs[(size_t)grow * D + nt * 16 + nn] = f2bs(c);
            pel[r] = fmaf(c, vav[nt], pel[r]);
            per_[r] = fmaf(c, vbv[nt], per_[r]);
        }
    }
#pragma unroll
    for (int r = 0; r < 4; ++r) {
#pragma unroll
        for (int mask = 1; mask < 16; mask <<= 1) {
            pel[r]  += __shfl_xor(pel[r],  mask, 64);
            per_[r] += __shfl_xor(per_[r], mask, 64);
        }
        const int grow = row0 + q * 4 + r;
        if (nn == 0 && grow < N_NODE) {
            el_o[grow] = pel[r];
            er_o[grow] = per_[r];
        }
    }
}

// ---------------------------------------------------------------- binned CSR build
// Round-9 lesson: 900k random 2B stores + 900k random atomics -> 42MB of
// partial-line writebacks across 8 non-coherent XCDs (23x amplification,
// 47us). Replacement: 2-level binned sort; every global write is a
// block-clustered run (1-2 lines per run, single XCD) -> ~2x amplification.

// K1: per-block LDS histogram of bins (bin = row>>8), 235 global adds/block
__global__ __launch_bounds__(256) void binct(
    const int* __restrict__ dst_rev, const int* __restrict__ dst_ind,
    const int* __restrict__ dst_dd, int* __restrict__ bin_cnt) {
    __shared__ int h[NBIN];
    const int tid = threadIdx.x;
    for (int i = tid; i < NBIN; i += 256) h[i] = 0;
    __syncthreads();
    const int base = blockIdx.x * CHUNK;
    const int lim = min(base + CHUNK, 3 * NEDGE);
    for (int i = base + tid; i < lim; i += 256) {
        const int t = (i >= 2 * NEDGE) ? 2 : (i >= NEDGE ? 1 : 0);
        const int e = i - t * NEDGE;
        const int d = (t == 0 ? dst_rev : (t == 1 ? dst_ind : dst_dd))[e];
        atomicAdd(&h[(t * N_NODE + d) >> 8], 1);
    }
    __syncthreads();
    for (int i = tid; i < NBIN; i += 256)
        if (h[i]) atomicAdd(&bin_cnt[i], h[i]);
}

// K2: one block scans the 235 bin counts -> bin_base (236 entries) + cursor
__global__ __launch_bounds__(256) void binscan(
    const int* __restrict__ bin_cnt, int* __restrict__ bin_base,
    int* __restrict__ bin_cursor, int* __restrict__ row_ptr) {
    __shared__ int wsum[4];
    const int tid = threadIdx.x;
    const int lane = tid & 63, wave = tid >> 6;
    int v = (tid < NBIN) ? bin_cnt[tid] : 0;
    const int orig = v;
#pragma unroll
    for (int off = 1; off < 64; off <<= 1) {
        int t = __shfl_up(v, off, 64);
        if (lane >= off) v += t;
    }
    if (lane == 63) wsum[wave] = v;
    __syncthreads();
    if (tid == 0) {
        int a = 0;
#pragma unroll
        for (int w = 0; w < 4; ++w) { int t = wsum[w]; wsum[w] = a; a += t; }
    }
    __syncthreads();
    const int incl = wsum[wave] + v;
    const int excl = incl - orig;
    if (tid < NBIN) { bin_base[tid] = excl; bin_cursor[tid] = excl; }
    if (tid == 255) { bin_base[NBIN] = incl; row_ptr[NROW] = 3 * NEDGE; }
}

// K3: block reserves one contiguous run per bin, streams its 4096 edges into
// the runs via LDS cursors. Payload u32 = (row16 << 16) | gsrc16.
__global__ __launch_bounds__(256) void binscat(
    const int* __restrict__ src_rev, const int* __restrict__ dst_rev,
    const int* __restrict__ src_ind, const int* __restrict__ dst_ind,
    const int* __restrict__ src_dd,  const int* __restrict__ dst_dd,
    int* __restrict__ bin_cursor, unsigned* __restrict__ bin_buf) {
    __shared__ int h[NBIN];
    __shared__ int runc[NBIN];
    const int tid = threadIdx.x;
    for (int i = tid; i < NBIN; i += 256) h[i] = 0;
    __syncthreads();
    const int base = blockIdx.x * CHUNK;
    const int lim = min(base + CHUNK, 3 * NEDGE);
    for (int i = base + tid; i < lim; i += 256) {
        const int t = (i >= 2 * NEDGE) ? 2 : (i >= NEDGE ? 1 : 0);
        const int e = i - t * NEDGE;
        const int d = (t == 0 ? dst_rev : (t == 1 ? dst_ind : dst_dd))[e];
        atomicAdd(&h[(t * N_NODE + d) >> 8], 1);
    }
    __syncthreads();
    for (int i = tid; i < NBIN; i += 256)
        runc[i] = h[i] ? atomicAdd(&bin_cursor[i], h[i]) : 0;
    __syncthreads();
    for (int i = base + tid; i < lim; i += 256) {
        const int t = (i >= 2 * NEDGE) ? 2 : (i >= NEDGE ? 1 : 0);
        const int e = i - t * NEDGE;
        const int sl = (t == 0 ? src_rev : (t == 1 ? src_ind : src_dd))[e];
        const int dl = (t == 0 ? dst_rev : (t == 1 ? dst_ind : dst_dd))[e];
        const int row = t * N_NODE + dl;
        const int slot = atomicAdd(&runc[row >> 8], 1);
        bin_buf[slot] = ((unsigned)row << 16) | (unsigned)(t * N_NODE + sl);
    }
}

// K4: one block per bin; 256-row LDS count+scan -> row_ptr (coalesced) and
// final 2B edge_src16 into the bin's private contiguous region.
__global__ __launch_bounds__(256) void binsort(
    const int* __restrict__ bin_base, const unsigned* __restrict__ bin_buf,
    int* __restrict__ row_ptr, unsigned short* __restrict__ edge_src16) {
    __shared__ int rowcnt[256];
    __shared__ int rankc[256];
    __shared__ int wsum[4];
    const int b = blockIdx.x;
    const int tid = threadIdx.x;
    const int beg = bin_base[b], end = bin_base[b + 1];
    rowcnt[tid] = 0;
    __syncthreads();
    for (int i = beg + tid; i < end; i += 256)
        atomicAdd(&rowcnt[(bin_buf[i] >> 16) & 255], 1);
    __syncthreads();
    // exclusive scan of rowcnt
    const int lane = tid & 63, wave = tid >> 6;
    int v = rowcnt[tid];
    const int orig = v;
#pragma unroll
    for (int off = 1; off < 64; off <<= 1) {
        int t = __shfl_up(v, off, 64);
        if (lane >= off) v += t;
    }
    if (lane == 63) wsum[wave] = v;
    __syncthreads();
    if (tid == 0) {
        int a = 0;
#pragma unroll
        for (int w = 0; w < 4; ++w) { int t = wsum[w]; wsum[w] = a; a += t; }
    }
    __syncthreads();
    const int excl = wsum[wave] + v - orig;
    const int row = b * 256 + tid;
    if (row < NROW) row_ptr[row] = beg + excl;
    rankc[tid] = beg + excl;
    __syncthreads();
    for (int i = beg + tid; i < end; i += 256) {
        const unsigned u = bin_buf[i];
        const int slot = atomicAdd(&rankc[(u >> 16) & 255], 1);
        edge_src16[slot] = (unsigned short)(u & 0xFFFFu);
    }
}

// ---------------------------------------------------------------- gather
// pass 1 recomputes pe per lane-owned edge and wave-reduces the softmax
// denominator (deterministic); pass 2 broadcasts (src, pe) via shfl and
// gathers Wh rows with x4 unroll.
__device__ __forceinline__ void do_range(
    const unsigned short* __restrict__ edge_src16,
    const float* __restrict__ el_all, float er_r,
    const bf16* __restrict__ Wh_all,
    int beg, int end, int lane, float& a0, float& a1) {
    if (end <= beg) return;

    float ssum = 0.f;
    for (int base = beg; base < end; base += 64) {
        const int m = min(end - base, 64);
        if (lane < m) {
            const int sr = edge_src16[base + lane];
            float v = el_all[sr] + er_r;
            v = v > 0.f ? v : 0.01f * v;
            ssum += __expf(v);
        }
    }
#pragma unroll
    for (int off = 32; off > 0; off >>= 1) ssum += __shfl_down(ssum, off, 64);
    const float inv = 1.0f / __shfl(ssum, 0, 64);

    for (int base = beg; base < end; base += 64) {
        const int m = min(end - base, 64);
        int msrc = 0; float mpe = 0.f;
        if (lane < m) {
            msrc = edge_src16[base + lane];
            float v = el_all[msrc] + er_r;
            v = v > 0.f ? v : 0.01f * v;
            mpe = __expf(v);
        }
        int t = 0;
        for (; t + 4 <= m; t += 4) {
            const int s0 = __shfl(msrc, t,     64);
            const int s1 = __shfl(msrc, t + 1, 64);
            const int s2 = __shfl(msrc, t + 2, 64);
            const int s3 = __shfl(msrc, t + 3, 64);
            const float c0 = __shfl(mpe, t,     64) * inv;
            const float c1 = __shfl(mpe, t + 1, 64) * inv;
            const float c2 = __shfl(mpe, t + 2, 64) * inv;
            const float c3 = __shfl(mpe, t + 3, 64) * inv;
            const unsigned u0 = ((const unsigned*)(Wh_all + (size_t)s0 * D))[lane];
            const unsigned u1 = ((const unsigned*)(Wh_all + (size_t)s1 * D))[lane];
            const unsigned u2 = ((const unsigned*)(Wh_all + (size_t)s2 * D))[lane];
            const unsigned u3 = ((const unsigned*)(Wh_all + (size_t)s3 * D))[lane];
            a0 = fmaf(c0, __uint_as_float(u0 << 16), a0);
            a1 = fmaf(c0, __uint_as_float(u0 & 0xFFFF0000u), a1);
            a0 = fmaf(c1, __uint_as_float(u1 << 16), a0);
            a1 = fmaf(c1, __uint_as_float(u1 & 0xFFFF0000u), a1);
            a0 = fmaf(c2, __uint_as_float(u2 << 16), a0);
            a1 = fmaf(c2, __uint_as_float(u2 & 0xFFFF0000u), a1);
            a0 = fmaf(c3, __uint_as_float(u3 << 16), a0);
            a1 = fmaf(c3, __uint_as_float(u3 & 0xFFFF0000u), a1);
        }
        for (; t < m; ++t) {
            const int s0 = __shfl(msrc, t, 64);
            const float c0 = __shfl(mpe, t, 64) * inv;
            const unsigned u0 = ((const unsigned*)(Wh_all + (size_t)s0 * D))[lane];
            a0 = fmaf(c0, __uint_as_float(u0 << 16), a0);
            a1 = fmaf(c0, __uint_as_float(u0 & 0xFFFF0000u), a1);
        }
    }
}

// One wave per OUTPUT row w in [0,40000): w<20000 -> h_drug (CSR row w, rev);
// w>=20000 -> h_disease (CSR rows w [ind] and w+20000 [dd]).
__global__ __launch_bounds__(256) void gather_all(
    const int* __restrict__ row_ptr, const unsigned short* __restrict__ edge_src16,
    const float* __restrict__ el_all, const float* __restrict__ er_all,
    const bf16* __restrict__ Wh_all, float* __restrict__ out) {
    const int w = blockIdx.x * (blockDim.x >> 6) + (threadIdx.x >> 6);
    const int lane = threadIdx.x & 63;
    if (w >= 2 * N_NODE) return;

    float a0 = 0.f, a1 = 0.f;
    do_range(edge_src16, el_all, er_all[w], Wh_all,
             row_ptr[w], row_ptr[w + 1], lane, a0, a1);
    if (w >= N_NODE) {
        const int r = w + N_NODE;
        do_range(edge_src16, el_all, er_all[r], Wh_all,
                 row_ptr[r], row_ptr[r + 1], lane, a0, a1);
    }
    ((float2*)(out + (size_t)w * D))[lane] = make_float2(a0, a1);
}

extern "C" void kernel_launch(void* const* d_in, const int* in_sizes, int n_in,
                              void* d_out, int out_size, void* d_ws, size_t ws_size,
                              hipStream_t stream) {
    const float* feat_drug    = (const float*)d_in[0];
    const float* feat_disease = (const float*)d_in[1];
    const float* W_ind = (const float*)d_in[2];
    const float* b_ind = (const float*)d_in[3];
    const float* a_ind = (const float*)d_in[4];
    const float* W_rev = (const float*)d_in[5];
    const float* b_rev = (const float*)d_in[6];
    const float* a_rev = (const float*)d_in[7];
    const float* W_dd  = (const float*)d_in[8];
    const float* b_dd  = (const float*)d_in[9];
    const float* a_dd  = (const float*)d_in[10];
    const int* src_ind = (const int*)d_in[11];
    const int* dst_ind = (const int*)d_in[12];
    const int* src_rev = (const int*)d_in[13];
    const int* dst_rev = (const int*)d_in[14];
    const int* src_dd  = (const int*)d_in[15];
    const int* dst_dd  = (const int*)d_in[16];
    float* out = (float*)d_out;
    (void)in_sizes; (void)n_in; (void)out_size; (void)ws_size;

    // ---- workspace: ~21.5 MB ----
    char* w = (char*)d_ws;
    bf16*  Wh_all     = (bf16*)w;                      // 15,360,000 B [rev|ind|dd]
    float* el_all     = (float*)(w + 15360000);        // 240,000 B
    float* er_all     = (float*)(w + 15600000);        // 240,000 B
    int*   row_ptr    = (int*)(w + 15840000);          // 240,004 -> pad 240,032
    int*   bin_cnt    = (int*)(w + 16080032);          // 1,024 B
    int*   bin_base   = (int*)(w + 16081056);          // 1,024 B (236 entries)
    int*   bin_cursor = (int*)(w + 16082080);          // 1,024 B
    unsigned* bin_buf = (unsigned*)(w + 16083104);     // 3,604,480 B
    unsigned short* edge_src16 = (unsigned short*)(w + 19687584); // 1,800,000 B

    const int gb = (2 * N_NODE + 3) / 4;               // gather: 4 waves/block

    // 1. all three GEMMs + projections in one MFMA launch
    gemm_mfma_all<<<3 * GBE, 256, 0, stream>>>(
        feat_drug, feat_disease, W_ind, b_ind, a_ind,
        W_rev, b_rev, a_rev, W_dd, b_dd, a_dd, Wh_all, el_all, er_all);

    // 2. binned CSR build (write-clustered; no random-line scatter)
    hipMemsetAsync(bin_cnt, 0, NBIN * sizeof(int), stream);
    binct<<<NB3, 256, 0, stream>>>(dst_rev, dst_ind, dst_dd, bin_cnt);
    binscan<<<1, 256, 0, stream>>>(bin_cnt, bin_base, bin_cursor, row_ptr);
    binscat<<<NB3, 256, 0, stream>>>(src_rev, dst_rev, src_ind, dst_ind,
                                     src_dd, dst_dd, bin_cursor, bin_buf);
    binsort<<<NBIN, 256, 0, stream>>>(bin_base, bin_buf, row_ptr, edge_src16);

    // 3. one gather: 40000 output rows, disease rows merge ind+dd in-register
    gather_all<<<gb, 256, 0, stream>>>(row_ptr, edge_src16, el_all, er_all,
                                       Wh_all, out);
}

// Round 11
// 181.346 us; speedup vs baseline: 3.2875x; 1.0745x over previous
//
#include <hip/hip_runtime.h>
#include <hip/hip_bf16.h>

typedef __hip_bfloat16 bf16;
typedef __attribute__((ext_vector_type(8))) short bf16x8;
typedef __attribute__((ext_vector_type(4))) float f32x4;

#define N_NODE 20000
#define D      128
#define NEDGE  300000
#define NROW   (3 * N_NODE)          // CSR rows: [rev | ind | dd] x dst-node
#define NBIN   ((NROW + 255) >> 8)   // 235 bins of 256 rows
#define NB3    220                   // bin-hist / binscat blocks (220*4096 >= 900000)
#define CHUNK  4096
#define GBE    ((N_NODE + 63) / 64)  // gemm blocks per etype = 313
#define GEMMB  (3 * GBE)             // 939
#define WT_LD  132                   // padded LDS leading dim (bank-conflict-free)

__device__ __forceinline__ short f2bs(float x) {
    bf16 h = __float2bfloat16(x);
    short s; __builtin_memcpy(&s, &h, 2); return s;
}

// ================================================================ K_A
// Fused: blocks [0, GEMMB) do the 3 MFMA GEMMs + projections; blocks
// [GEMMB, GEMMB+NB3) histogram the edge bins (per-block partials, NO atomics,
// no zero-init needed) — fully overlapped, one launch.
// GEMM: block = 4 waves x 16 rows; W transposed+padded bf16 in LDS; 32x
// mfma_16x16x32_bf16/wave. Layouts (m89/m120): A[m=lane&15][k=quad*8+j];
// B[k=quad*8+j][n=lane&15]; D: row=quad*4+reg, col=lane&15. el/er cross-
// wiring: t=0 Wh_rev->el[rev],er[ind]; t=1 Wh_ind->el[ind],er[rev]; t=2 dd.
union SharedA {
    short Wt[D * WT_LD];   // 33,792 B (gemm branch)
    int   h[NBIN];         //    940 B (hist branch)
};

__global__ __launch_bounds__(256) void gemm_and_count(
    const float* __restrict__ feat_drug, const float* __restrict__ feat_dis,
    const float* __restrict__ W_ind, const float* __restrict__ b_ind,
    const float* __restrict__ a_ind,
    const float* __restrict__ W_rev, const float* __restrict__ b_rev,
    const float* __restrict__ a_rev,
    const float* __restrict__ W_dd, const float* __restrict__ b_dd,
    const float* __restrict__ a_dd,
    const int* __restrict__ dst_rev, const int* __restrict__ dst_ind,
    const int* __restrict__ dst_dd,
    bf16* __restrict__ Wh_all, float* __restrict__ el_all,
    float* __restrict__ er_all, int* __restrict__ bin_part) {
    __shared__ SharedA su;
    const int tid = threadIdx.x;

    if (blockIdx.x >= GEMMB) {
        // ---------- bin histogram branch ----------
        const int blk = blockIdx.x - GEMMB;
        for (int i = tid; i < NBIN; i += 256) su.h[i] = 0;
        __syncthreads();
        const int base = blk * CHUNK;
        const int lim = min(base + CHUNK, 3 * NEDGE);
        for (int i = base + tid; i < lim; i += 256) {
            const int t = (i >= 2 * NEDGE) ? 2 : (i >= NEDGE ? 1 : 0);
            const int e = i - t * NEDGE;
            const int d = (t == 0 ? dst_rev : (t == 1 ? dst_ind : dst_dd))[e];
            atomicAdd(&su.h[(t * N_NODE + d) >> 8], 1);
        }
        __syncthreads();
        for (int i = tid; i < NBIN; i += 256)
            bin_part[blk * NBIN + i] = su.h[i];
        return;
    }

    // ---------- GEMM branch ----------
    const int t  = blockIdx.x / GBE;
    const int mb = blockIdx.x - t * GBE;

    const float *feat, *W, *bias, *va, *vb;
    float *el_o, *er_o;
    if (t == 0)      { feat = feat_dis;  W = W_rev; bias = b_rev; va = a_rev; vb = a_ind + D; el_o = el_all;              er_o = er_all + N_NODE; }
    else if (t == 1) { feat = feat_drug; W = W_ind; bias = b_ind; va = a_ind; vb = a_rev + D; el_o = el_all + N_NODE;     er_o = er_all; }
    else             { feat = feat_dis;  W = W_dd;  bias = b_dd;  va = a_dd;  vb = a_dd + D;  el_o = el_all + 2 * N_NODE; er_o = er_all + 2 * N_NODE; }
    bf16* wh_o = Wh_all + (size_t)t * N_NODE * D;

    for (int i = tid * 4; i < D * D; i += 1024) {
        const float4 wv = *(const float4*)(W + i);
        const int k = i >> 7, n = i & (D - 1);
        su.Wt[(n + 0) * WT_LD + k] = f2bs(wv.x);
        su.Wt[(n + 1) * WT_LD + k] = f2bs(wv.y);
        su.Wt[(n + 2) * WT_LD + k] = f2bs(wv.z);
        su.Wt[(n + 3) * WT_LD + k] = f2bs(wv.w);
    }
    __syncthreads();

    const int wave = tid >> 6, lane = tid & 63;
    const int q = lane >> 4, nn = lane & 15;
    const int row0 = mb * 64 + wave * 16;
    const int arow = min(row0 + nn, N_NODE - 1);

    f32x4 acc[8];
#pragma unroll
    for (int nt = 0; nt < 8; ++nt) acc[nt] = (f32x4){0.f, 0.f, 0.f, 0.f};

#pragma unroll
    for (int ks = 0; ks < 4; ++ks) {
        const float* ap = feat + (size_t)arow * D + ks * 32 + q * 8;
        const float4 fa = *(const float4*)ap;
        const float4 fb = *(const float4*)(ap + 4);
        bf16x8 afrag;
        afrag[0] = f2bs(fa.x); afrag[1] = f2bs(fa.y);
        afrag[2] = f2bs(fa.z); afrag[3] = f2bs(fa.w);
        afrag[4] = f2bs(fb.x); afrag[5] = f2bs(fb.y);
        afrag[6] = f2bs(fb.z); afrag[7] = f2bs(fb.w);
#pragma unroll
        for (int nt = 0; nt < 8; ++nt) {
            const bf16x8 bfrag =
                *(const bf16x8*)(&su.Wt[(nt * 16 + nn) * WT_LD + ks * 32 + q * 8]);
            acc[nt] = __builtin_amdgcn_mfma_f32_16x16x32_bf16(afrag, bfrag,
                                                              acc[nt], 0, 0, 0);
        }
    }

    float biasv[8], vav[8], vbv[8];
#pragma unroll
    for (int nt = 0; nt < 8; ++nt) {
        const int col = nt * 16 + nn;
        biasv[nt] = bias[col]; vav[nt] = va[col]; vbv[nt] = vb[col];
    }
    float pel[4] = {0.f, 0.f, 0.f, 0.f};
    float per_[4] = {0.f, 0.f, 0.f, 0.f};
    short* whs = (short*)wh_o;
#pragma unroll
    for (int nt = 0; nt < 8; ++nt) {
#pragma unroll
        for (int r = 0; r < 4; ++r) {
            const float c = acc[nt][r] + biasv[nt];
            const int grow = row0 + q * 4 + r;
            if (grow < N_NODE)
                whs[(size_t)grow * D + nt * 16 + nn] = f2bs(c);
            pel[r] = fmaf(c, vav[nt], pel[r]);
            per_[r] = fmaf(c, vbv[nt], per_[r]);
        }
    }
#pragma unroll
    for (int r = 0; r < 4; ++r) {
#pragma unroll
        for (int mask = 1; mask < 16; mask <<= 1) {
            pel[r]  += __shfl_xor(pel[r],  mask, 64);
            per_[r] += __shfl_xor(per_[r], mask, 64);
        }
        const int grow = row0 + q * 4 + r;
        if (nn == 0 && grow < N_NODE) {
            el_o[grow] = pel[r];
            er_o[grow] = per_[r];
        }
    }
}

// ================================================================ K_B binscat
// Each block re-derives (from the partial-hist table, L2-hot ~207KB): the bin
// totals, their exclusive scan (bin_base), and its own deterministic run
// offset  bin_base[b] + sum_{j<blk} partial[j][b]  — no global atomics at
// all. Streams its 4096 edges into per-bin runs via LDS cursors. Payload
// u32 = (row16 << 16) | gsrc16. Block 0 publishes bin_base + row_ptr[NROW].
__global__ __launch_bounds__(256) void binscat(
    const int* __restrict__ src_rev, const int* __restrict__ dst_rev,
    const int* __restrict__ src_ind, const int* __restrict__ dst_ind,
    const int* __restrict__ src_dd,  const int* __restrict__ dst_dd,
    const int* __restrict__ bin_part, int* __restrict__ bin_base_g,
    int* __restrict__ row_ptr, unsigned* __restrict__ bin_buf) {
    __shared__ int runc[NBIN];
    __shared__ int wsum[4];
    const int blk = blockIdx.x;
    const int tid = threadIdx.x;
    const int lane = tid & 63, wave = tid >> 6;

    int tot = 0, pre = 0;
    if (tid < NBIN) {
        for (int j = 0; j < NB3; ++j) {
            const int c = bin_part[j * NBIN + tid];
            tot += c;
            pre += (j < blk) ? c : 0;
        }
    }
    // exclusive scan of tot across the 235 bins
    int v = (tid < NBIN) ? tot : 0;
    const int orig = v;
#pragma unroll
    for (int off = 1; off < 64; off <<= 1) {
        int t = __shfl_up(v, off, 64);
        if (lane >= off) v += t;
    }
    if (lane == 63) wsum[wave] = v;
    __syncthreads();
    if (tid == 0) {
        int a = 0;
#pragma unroll
        for (int w = 0; w < 4; ++w) { int t = wsum[w]; wsum[w] = a; a += t; }
    }
    __syncthreads();
    const int excl = wsum[wave] + v - orig;
    if (tid < NBIN) runc[tid] = excl + pre;
    if (blk == 0) {
        if (tid < NBIN) bin_base_g[tid] = excl;
        if (tid == 0) { bin_base_g[NBIN] = 3 * NEDGE; row_ptr[NROW] = 3 * NEDGE; }
    }
    __syncthreads();

    const int base = blk * CHUNK;
    const int lim = min(base + CHUNK, 3 * NEDGE);
    for (int i = base + tid; i < lim; i += 256) {
        const int t = (i >= 2 * NEDGE) ? 2 : (i >= NEDGE ? 1 : 0);
        const int e = i - t * NEDGE;
        const int sl = (t == 0 ? src_rev : (t == 1 ? src_ind : src_dd))[e];
        const int dl = (t == 0 ? dst_rev : (t == 1 ? dst_ind : dst_dd))[e];
        const int row = t * N_NODE + dl;
        const int slot = atomicAdd(&runc[row >> 8], 1);
        bin_buf[slot] = ((unsigned)row << 16) | (unsigned)(t * N_NODE + sl);
    }
}

// ================================================================ K_C binsort
// One block per bin; 256-row LDS count+scan -> row_ptr (coalesced) and final
// 2B edge_src16 into the bin's private contiguous region (single XCD).
__global__ __launch_bounds__(256) void binsort(
    const int* __restrict__ bin_base, const unsigned* __restrict__ bin_buf,
    int* __restrict__ row_ptr, unsigned short* __restrict__ edge_src16) {
    __shared__ int rowcnt[256];
    __shared__ int rankc[256];
    __shared__ int wsum[4];
    const int b = blockIdx.x;
    const int tid = threadIdx.x;
    const int beg = bin_base[b], end = bin_base[b + 1];
    rowcnt[tid] = 0;
    __syncthreads();
    for (int i = beg + tid; i < end; i += 256)
        atomicAdd(&rowcnt[(bin_buf[i] >> 16) & 255], 1);
    __syncthreads();
    const int lane = tid & 63, wave = tid >> 6;
    int v = rowcnt[tid];
    const int orig = v;
#pragma unroll
    for (int off = 1; off < 64; off <<= 1) {
        int t = __shfl_up(v, off, 64);
        if (lane >= off) v += t;
    }
    if (lane == 63) wsum[wave] = v;
    __syncthreads();
    if (tid == 0) {
        int a = 0;
#pragma unroll
        for (int w = 0; w < 4; ++w) { int t = wsum[w]; wsum[w] = a; a += t; }
    }
    __syncthreads();
    const int excl = wsum[wave] + v - orig;
    const int row = b * 256 + tid;
    if (row < NROW) row_ptr[row] = beg + excl;
    rankc[tid] = beg + excl;
    __syncthreads();
    for (int i = beg + tid; i < end; i += 256) {
        const unsigned u = bin_buf[i];
        const int slot = atomicAdd(&rankc[(u >> 16) & 255], 1);
        edge_src16[slot] = (unsigned short)(u & 0xFFFFu);
    }
}

// ================================================================ K_D gather
__device__ __forceinline__ void process_chunk(
    int msrc, float mpe, int m, float inv, int lane,
    const bf16* __restrict__ Wh_all, float& a0, float& a1) {
    int t = 0;
    for (; t + 4 <= m; t += 4) {
        const int s0 = __shfl(msrc, t,     64);
        const int s1 = __shfl(msrc, t + 1, 64);
        const int s2 = __shfl(msrc, t + 2, 64);
        const int s3 = __shfl(msrc, t + 3, 64);
        const float c0 = __shfl(mpe, t,     64) * inv;
        const float c1 = __shfl(mpe, t + 1, 64) * inv;
        const float c2 = __shfl(mpe, t + 2, 64) * inv;
        const float c3 = __shfl(mpe, t + 3, 64) * inv;
        const unsigned u0 = ((const unsigned*)(Wh_all + (size_t)s0 * D))[lane];
        const unsigned u1 = ((const unsigned*)(Wh_all + (size_t)s1 * D))[lane];
        const unsigned u2 = ((const unsigned*)(Wh_all + (size_t)s2 * D))[lane];
        const unsigned u3 = ((const unsigned*)(Wh_all + (size_t)s3 * D))[lane];
        a0 = fmaf(c0, __uint_as_float(u0 << 16), a0);
        a1 = fmaf(c0, __uint_as_float(u0 & 0xFFFF0000u), a1);
        a0 = fmaf(c1, __uint_as_float(u1 << 16), a0);
        a1 = fmaf(c1, __uint_as_float(u1 & 0xFFFF0000u), a1);
        a0 = fmaf(c2, __uint_as_float(u2 << 16), a0);
        a1 = fmaf(c2, __uint_as_float(u2 & 0xFFFF0000u), a1);
        a0 = fmaf(c3, __uint_as_float(u3 << 16), a0);
        a1 = fmaf(c3, __uint_as_float(u3 & 0xFFFF0000u), a1);
    }
    for (; t < m; ++t) {
        const int s0 = __shfl(msrc, t, 64);
        const float c0 = __shfl(mpe, t, 64) * inv;
        const unsigned u0 = ((const unsigned*)(Wh_all + (size_t)s0 * D))[lane];
        a0 = fmaf(c0, __uint_as_float(u0 << 16), a0);
        a1 = fmaf(c0, __uint_as_float(u0 & 0xFFFF0000u), a1);
    }
}

// pass 1 loads chunk-0 edge meta into registers (avg degree ~15 < 64, so for
// nearly every row pass 2 reuses them — no reload/re-exp); deterministic
// wave-reduced softmax denominator.
__device__ __forceinline__ void do_range(
    const unsigned short* __restrict__ edge_src16,
    const float* __restrict__ el_all, float er_r,
    const bf16* __restrict__ Wh_all,
    int beg, int end, int lane, float& a0, float& a1) {
    if (end <= beg) return;
    const int deg = end - beg;
    const int m0 = min(deg, 64);

    int msrc0 = 0; float mpe0 = 0.f;
    if (lane < m0) {
        msrc0 = edge_src16[beg + lane];
        float v = el_all[msrc0] + er_r;
        v = v > 0.f ? v : 0.01f * v;
        mpe0 = __expf(v);
    }
    float ssum = mpe0;
    for (int base = beg + 64; base < end; base += 64) {
        const int m = min(end - base, 64);
        if (lane < m) {
            const int sr = edge_src16[base + lane];
            float v = el_all[sr] + er_r;
            v = v > 0.f ? v : 0.01f * v;
            ssum += __expf(v);
        }
    }
#pragma unroll
    for (int off = 32; off > 0; off >>= 1) ssum += __shfl_down(ssum, off, 64);
    const float inv = 1.0f / __shfl(ssum, 0, 64);

    process_chunk(msrc0, mpe0, m0, inv, lane, Wh_all, a0, a1);
    for (int base = beg + 64; base < end; base += 64) {
        const int m = min(end - base, 64);
        int msrc = 0; float mpe = 0.f;
        if (lane < m) {
            msrc = edge_src16[base + lane];
            float v = el_all[msrc] + er_r;
            v = v > 0.f ? v : 0.01f * v;
            mpe = __expf(v);
        }
        process_chunk(msrc, mpe, m, inv, lane, Wh_all, a0, a1);
    }
}

// One wave per OUTPUT row w in [0,40000): w<20000 -> h_drug (CSR row w, rev);
// w>=20000 -> h_disease (CSR rows w [ind] and w+20000 [dd]).
__global__ __launch_bounds__(256) void gather_all(
    const int* __restrict__ row_ptr, const unsigned short* __restrict__ edge_src16,
    const float* __restrict__ el_all, const float* __restrict__ er_all,
    const bf16* __restrict__ Wh_all, float* __restrict__ out) {
    const int w = blockIdx.x * (blockDim.x >> 6) + (threadIdx.x >> 6);
    const int lane = threadIdx.x & 63;
    if (w >= 2 * N_NODE) return;

    float a0 = 0.f, a1 = 0.f;
    do_range(edge_src16, el_all, er_all[w], Wh_all,
             row_ptr[w], row_ptr[w + 1], lane, a0, a1);
    if (w >= N_NODE) {
        const int r = w + N_NODE;
        do_range(edge_src16, el_all, er_all[r], Wh_all,
                 row_ptr[r], row_ptr[r + 1], lane, a0, a1);
    }
    ((float2*)(out + (size_t)w * D))[lane] = make_float2(a0, a1);
}

extern "C" void kernel_launch(void* const* d_in, const int* in_sizes, int n_in,
                              void* d_out, int out_size, void* d_ws, size_t ws_size,
                              hipStream_t stream) {
    const float* feat_drug    = (const float*)d_in[0];
    const float* feat_disease = (const float*)d_in[1];
    const float* W_ind = (const float*)d_in[2];
    const float* b_ind = (const float*)d_in[3];
    const float* a_ind = (const float*)d_in[4];
    const float* W_rev = (const float*)d_in[5];
    const float* b_rev = (const float*)d_in[6];
    const float* a_rev = (const float*)d_in[7];
    const float* W_dd  = (const float*)d_in[8];
    const float* b_dd  = (const float*)d_in[9];
    const float* a_dd  = (const float*)d_in[10];
    const int* src_ind = (const int*)d_in[11];
    const int* dst_ind = (const int*)d_in[12];
    const int* src_rev = (const int*)d_in[13];
    const int* dst_rev = (const int*)d_in[14];
    const int* src_dd  = (const int*)d_in[15];
    const int* dst_dd  = (const int*)d_in[16];
    float* out = (float*)d_out;
    (void)in_sizes; (void)n_in; (void)out_size; (void)ws_size;

    // ---- workspace: ~21.7 MB ----
    char* w = (char*)d_ws;
    bf16*  Wh_all   = (bf16*)w;                        // 15,360,000 B [rev|ind|dd]
    float* el_all   = (float*)(w + 15360000);          // 240,000 B
    float* er_all   = (float*)(w + 15600000);          // 240,000 B
    int*   row_ptr  = (int*)(w + 15840000);            // 240,004 -> pad 240,032
    int*   bin_base = (int*)(w + 16080032);            // 1,024 B (236 entries)
    int*   bin_part = (int*)(w + 16081056);            // 220*235*4 = 206,800 -> pad 206,816
    unsigned* bin_buf = (unsigned*)(w + 16287872);     // 3,600,000 B
    unsigned short* edge_src16 = (unsigned short*)(w + 19887872); // 1,800,000 B

    const int gb = (2 * N_NODE + 3) / 4;               // gather: 4 waves/block

    // K_A: 3 GEMMs + projections, overlapped with the bin histogram
    gemm_and_count<<<GEMMB + NB3, 256, 0, stream>>>(
        feat_drug, feat_disease, W_ind, b_ind, a_ind,
        W_rev, b_rev, a_rev, W_dd, b_dd, a_dd,
        dst_rev, dst_ind, dst_dd, Wh_all, el_all, er_all, bin_part);

    // K_B: deterministic binned scatter (scan derived in-kernel, no atomics)
    binscat<<<NB3, 256, 0, stream>>>(src_rev, dst_rev, src_ind, dst_ind,
                                     src_dd, dst_dd, bin_part, bin_base,
                                     row_ptr, bin_buf);

    // K_C: per-bin row sort -> row_ptr + final edge_src16
    binsort<<<NBIN, 256, 0, stream>>>(bin_base, bin_buf, row_ptr, edge_src16);

    // K_D: one gather, 40000 output rows; disease rows merge ind+dd in-register
    gather_all<<<gb, 256, 0, stream>>>(row_ptr, edge_src16, el_all, er_all,
                                       Wh_all, out);
}